// Round 7
// baseline (407.614 us; speedup 1.0000x reference)
//
#include <hip/hip_runtime.h>

#define HDIM 1024
#define TLEN 2048
#define NBATCH 16

typedef short bf16x8 __attribute__((ext_vector_type(8)));
typedef float floatx4 __attribute__((ext_vector_type(4)));
typedef unsigned short ushort_t;

__device__ __forceinline__ ushort_t f2bf(float x) {
  unsigned u = __float_as_uint(x);
  unsigned r = (u + 0x7FFFu + ((u >> 16) & 1u)) >> 16;
  return (ushort_t)r;
}
__device__ __forceinline__ float bf2f(ushort_t h) {
  return __uint_as_float(((unsigned)h) << 16);
}

// async global->LDS, 16B per lane; LDS dest = wave-uniform base + lane*16 (linear)
typedef __attribute__((address_space(1))) void gvoid_t;
typedef __attribute__((address_space(3))) void lvoid_t;
__device__ __forceinline__ void gload16(const ushort_t* g, ushort_t* l) {
  __builtin_amdgcn_global_load_lds((gvoid_t*)g, (lvoid_t*)l, 16, 0, 0);
}

#define TSTR 71  // transpose stride (64x64 tiles)

// ---------------- prep: split A into bf16 h/m/l (+transposed); init V col0 / U row0 ----------------
__global__ __launch_bounds__(256) void prep(const float* __restrict__ A,
    const float* __restrict__ Bv, const float* __restrict__ Cv,
    ushort_t* __restrict__ Ah, ushort_t* __restrict__ Am, ushort_t* __restrict__ Al,
    ushort_t* __restrict__ ATh, ushort_t* __restrict__ ATm, ushort_t* __restrict__ ATl,
    float* __restrict__ Vc, float* __restrict__ U) {
  __shared__ ushort_t Lt[3 * 64 * TSTR];
  const int tid = threadIdx.x;
  if (blockIdx.x >= 256) {  // init blocks
    int i = (blockIdx.x - 256) * 256 + tid;
    if (i < HDIM) Vc[i] = Bv[i];
    else U[i - HDIM] = Cv[i - HDIM];
    return;
  }
  const int row0 = (blockIdx.x >> 4) * 64, col0 = (blockIdx.x & 15) * 64;
  const int r = tid >> 2, q = tid & 3;
  ushort_t hs[16], ms[16], ls[16];
#pragma unroll
  for (int c4 = 0; c4 < 4; ++c4) {
    float4 a = *(const float4*)&A[(row0 + r) * HDIM + col0 + q * 16 + c4 * 4];
    float av[4] = {a.x, a.y, a.z, a.w};
#pragma unroll
    for (int i = 0; i < 4; ++i) {
      float z = av[i];
      ushort_t h = f2bf(z); float r1 = z - bf2f(h);
      ushort_t mq = f2bf(r1); float r2 = r1 - bf2f(mq);
      ushort_t lq = f2bf(r2);
      hs[c4 * 4 + i] = h; ms[c4 * 4 + i] = mq; ls[c4 * 4 + i] = lq;
    }
  }
  size_t go = (size_t)(row0 + r) * HDIM + col0 + q * 16;
  *(uint4*)&Ah[go] = ((uint4*)hs)[0]; *(uint4*)&Ah[go + 8] = ((uint4*)hs)[1];
  *(uint4*)&Am[go] = ((uint4*)ms)[0]; *(uint4*)&Am[go + 8] = ((uint4*)ms)[1];
  *(uint4*)&Al[go] = ((uint4*)ls)[0]; *(uint4*)&Al[go + 8] = ((uint4*)ls)[1];
#pragma unroll
  for (int i = 0; i < 16; ++i) {
    int c = q * 16 + i;
    Lt[0 * 64 * TSTR + r * TSTR + c] = hs[i];
    Lt[1 * 64 * TSTR + r * TSTR + c] = ms[i];
    Lt[2 * 64 * TSTR + r * TSTR + c] = ls[i];
  }
  __syncthreads();
  const int c = tid >> 2, q2 = tid & 3;
  ushort_t* dsts[3] = {ATh, ATm, ATl};
#pragma unroll
  for (int s = 0; s < 3; ++s) {
    ushort_t tmp[16];
#pragma unroll
    for (int rr = 0; rr < 16; ++rr) tmp[rr] = Lt[s * 64 * TSTR + (q2 * 16 + rr) * TSTR + c];
    size_t gt = (size_t)(col0 + c) * HDIM + row0 + q2 * 16;
    *(uint4*)&dsts[s][gt] = ((uint4*)tmp)[0];
    *(uint4*)&dsts[s][gt + 8] = ((uint4*)tmp)[1];
  }
}

// ---------------- Z = X*X, 64x64 tiles (256 blocks, XCD-swizzled) + fused V/U tail ----------------
// SIX (sq1..4): BK=32 path.  FOUR (sq5..10): BK=64 path (swizzled slots, 16 barriers).
// Tails: DIRECT streaming (R5 form) — no LDS staging, no barriers; latency hidden by
// unrolled k-loop + multiple waves (R6's staged-V variant regressed ~+15-20 us).
template <int MODE, int NC, bool SIX, bool WRITEL, bool WROW>
__global__ __launch_bounds__(256) void sq_mfma(
    const ushort_t* __restrict__ Xh, const ushort_t* __restrict__ Xm,
    const ushort_t* __restrict__ Xl,
    const ushort_t* __restrict__ XTh, const ushort_t* __restrict__ XTm,
    const ushort_t* __restrict__ XTl,
    ushort_t* __restrict__ Zh, ushort_t* __restrict__ Zm, ushort_t* __restrict__ Zl,
    ushort_t* __restrict__ ZTh, ushort_t* __restrict__ ZTm, ushort_t* __restrict__ ZTl,
    const float* __restrict__ Af, const float* __restrict__ Bvf,
    float* __restrict__ VU) {
  constexpr int BK = SIX ? 32 : 64;
  constexpr int SLAB = 64 * BK;                 // elems per array per K-step buffer
  constexpr int BUFSTR = (SIX ? 6 : 4) * SLAB;
  constexpr int BBASE = (SIX ? 3 : 2) * SLAB;   // B-side slabs start here
  constexpr int LDS_ELEMS = 2 * BUFSTR;         // SIX: 48 KB, FOUR: 64 KB
  __shared__ __align__(16) ushort_t sm[LDS_ELEMS];
  const int tid = threadIdx.x;

  if (blockIdx.x >= 256) {  // ---- tail blocks: 256 blocks -> 1024 waves ----
    const int tb = blockIdx.x - 256;
    const int wv = tb * 4 + (tid >> 6);
    const int lane = tid & 63;
    if (MODE == 0) {
      float acc = 0.f;
      for (int k = lane; k < HDIM; k += 64) acc += Af[(size_t)wv * HDIM + k] * Bvf[k];
      for (int off = 32; off; off >>= 1) acc += __shfl_down(acc, off);
      if (lane == 0) VU[HDIM + wv] = acc;
    } else {
      const ushort_t* Ph = (MODE == 1) ? Xh : XTh;
      const ushort_t* Pm = (MODE == 1) ? Xm : XTm;
      float acc[NC];
#pragma unroll
      for (int n = 0; n < NC; ++n) acc[n] = 0.f;
      for (int k = lane; k < HDIM; k += 64) {
        float a = bf2f(Ph[(size_t)wv * HDIM + k]) + bf2f(Pm[(size_t)wv * HDIM + k]);
#pragma unroll
        for (int n = 0; n < NC; ++n) acc[n] += a * VU[(size_t)n * HDIM + k];
      }
#pragma unroll
      for (int n = 0; n < NC; ++n) {
        float s = acc[n];
        for (int off = 32; off; off >>= 1) s += __shfl_down(s, off);
        if (lane == 0) VU[(size_t)(NC + n) * HDIM + wv] = s;
      }
    }
    return;
  }

  // ---- squaring blocks: 16x16 grid of 64x64 tiles, XCD-rectangle swizzle ----
  const int bb = blockIdx.x;
  const int xcd = bb & 7, slot = bb >> 3;
  const int tr = 4 * (xcd >> 1) + (slot >> 3);
  const int tc = 8 * (xcd & 1) + (slot & 7);
  const int row0 = tr * 64, col0 = tc * 64;

  const int w = tid >> 6, l = tid & 63, li = l & 15, quad = l >> 4;

  floatx4 acc0 = {0.f, 0.f, 0.f, 0.f}, acc1 = acc0, acc2 = acc0, acc3 = acc0;

  ushort_t* lwb = &sm[w * 512];  // per-wave uniform LDS base (pass 0)

  if (SIX) {
    // ================= BK=32 path =================
    const int sr = tid >> 2, sq4 = tid & 3;
    const int aoff = (w * 16 + li) * 32 + quad * 8;
    const int b0o = (0 * 16 + li) * 32 + quad * 8;
    const int b1o = (1 * 16 + li) * 32 + quad * 8;
    const int b2o = (2 * 16 + li) * 32 + quad * 8;
    const int b3o = (3 * 16 + li) * 32 + quad * 8;

    const ushort_t* gAh = Xh + (size_t)(row0 + sr) * HDIM + sq4 * 8;
    const ushort_t* gAm = Xm + (size_t)(row0 + sr) * HDIM + sq4 * 8;
    const ushort_t* gAl = Xl + (size_t)(row0 + sr) * HDIM + sq4 * 8;
    const ushort_t* gBh = XTh + (size_t)(col0 + sr) * HDIM + sq4 * 8;
    const ushort_t* gBm = XTm + (size_t)(col0 + sr) * HDIM + sq4 * 8;
    const ushort_t* gBl = XTl + (size_t)(col0 + sr) * HDIM + sq4 * 8;

    {
      ushort_t* lb = lwb;
      gload16(gAh, lb);
      gload16(gAm, lb + SLAB);
      gload16(gAl, lb + 2 * SLAB);
      gload16(gBh, lb + BBASE);
      gload16(gBm, lb + BBASE + SLAB);
      gload16(gBl, lb + BBASE + 2 * SLAB);
    }
    __syncthreads();

    int cur = 0;
    for (int k0 = 0; k0 < HDIM; k0 += 32) {
      if (k0 + 32 < HDIM) {
        ushort_t* lb = lwb + (cur ^ 1) * BUFSTR;
        const int kn = k0 + 32;
        gload16(gAh + kn, lb);
        gload16(gAm + kn, lb + SLAB);
        gload16(gAl + kn, lb + 2 * SLAB);
        gload16(gBh + kn, lb + BBASE);
        gload16(gBm + kn, lb + BBASE + SLAB);
        gload16(gBl + kn, lb + BBASE + 2 * SLAB);
      }
      const int cb = cur * BUFSTR;
      bf16x8 ah = *(const bf16x8*)&sm[cb + aoff];
      bf16x8 am = *(const bf16x8*)&sm[cb + SLAB + aoff];
      bf16x8 al = *(const bf16x8*)&sm[cb + 2 * SLAB + aoff];
      {
        bf16x8 bh = *(const bf16x8*)&sm[cb + BBASE + b0o];
        bf16x8 bm = *(const bf16x8*)&sm[cb + BBASE + SLAB + b0o];
        bf16x8 bl = *(const bf16x8*)&sm[cb + BBASE + 2 * SLAB + b0o];
        acc0 = __builtin_amdgcn_mfma_f32_16x16x32_bf16(ah, bh, acc0, 0, 0, 0);
        acc0 = __builtin_amdgcn_mfma_f32_16x16x32_bf16(ah, bm, acc0, 0, 0, 0);
        acc0 = __builtin_amdgcn_mfma_f32_16x16x32_bf16(am, bh, acc0, 0, 0, 0);
        acc0 = __builtin_amdgcn_mfma_f32_16x16x32_bf16(am, bm, acc0, 0, 0, 0);
        acc0 = __builtin_amdgcn_mfma_f32_16x16x32_bf16(ah, bl, acc0, 0, 0, 0);
        acc0 = __builtin_amdgcn_mfma_f32_16x16x32_bf16(al, bh, acc0, 0, 0, 0);
      }
      {
        bf16x8 bh = *(const bf16x8*)&sm[cb + BBASE + b1o];
        bf16x8 bm = *(const bf16x8*)&sm[cb + BBASE + SLAB + b1o];
        bf16x8 bl = *(const bf16x8*)&sm[cb + BBASE + 2 * SLAB + b1o];
        acc1 = __builtin_amdgcn_mfma_f32_16x16x32_bf16(ah, bh, acc1, 0, 0, 0);
        acc1 = __builtin_amdgcn_mfma_f32_16x16x32_bf16(ah, bm, acc1, 0, 0, 0);
        acc1 = __builtin_amdgcn_mfma_f32_16x16x32_bf16(am, bh, acc1, 0, 0, 0);
        acc1 = __builtin_amdgcn_mfma_f32_16x16x32_bf16(am, bm, acc1, 0, 0, 0);
        acc1 = __builtin_amdgcn_mfma_f32_16x16x32_bf16(ah, bl, acc1, 0, 0, 0);
        acc1 = __builtin_amdgcn_mfma_f32_16x16x32_bf16(al, bh, acc1, 0, 0, 0);
      }
      {
        bf16x8 bh = *(const bf16x8*)&sm[cb + BBASE + b2o];
        bf16x8 bm = *(const bf16x8*)&sm[cb + BBASE + SLAB + b2o];
        bf16x8 bl = *(const bf16x8*)&sm[cb + BBASE + 2 * SLAB + b2o];
        acc2 = __builtin_amdgcn_mfma_f32_16x16x32_bf16(ah, bh, acc2, 0, 0, 0);
        acc2 = __builtin_amdgcn_mfma_f32_16x16x32_bf16(ah, bm, acc2, 0, 0, 0);
        acc2 = __builtin_amdgcn_mfma_f32_16x16x32_bf16(am, bh, acc2, 0, 0, 0);
        acc2 = __builtin_amdgcn_mfma_f32_16x16x32_bf16(am, bm, acc2, 0, 0, 0);
        acc2 = __builtin_amdgcn_mfma_f32_16x16x32_bf16(ah, bl, acc2, 0, 0, 0);
        acc2 = __builtin_amdgcn_mfma_f32_16x16x32_bf16(al, bh, acc2, 0, 0, 0);
      }
      {
        bf16x8 bh = *(const bf16x8*)&sm[cb + BBASE + b3o];
        bf16x8 bm = *(const bf16x8*)&sm[cb + BBASE + SLAB + b3o];
        bf16x8 bl = *(const bf16x8*)&sm[cb + BBASE + 2 * SLAB + b3o];
        acc3 = __builtin_amdgcn_mfma_f32_16x16x32_bf16(ah, bh, acc3, 0, 0, 0);
        acc3 = __builtin_amdgcn_mfma_f32_16x16x32_bf16(ah, bm, acc3, 0, 0, 0);
        acc3 = __builtin_amdgcn_mfma_f32_16x16x32_bf16(am, bh, acc3, 0, 0, 0);
        acc3 = __builtin_amdgcn_mfma_f32_16x16x32_bf16(am, bm, acc3, 0, 0, 0);
        acc3 = __builtin_amdgcn_mfma_f32_16x16x32_bf16(ah, bl, acc3, 0, 0, 0);
        acc3 = __builtin_amdgcn_mfma_f32_16x16x32_bf16(al, bh, acc3, 0, 0, 0);
      }
      __syncthreads();
      cur ^= 1;
    }
  } else {
    // ================= BK=64 path (swizzled slots, 16 barriers) =================
    const int sr8 = tid >> 3;                       // row 0..31 (pass 0); pass 1 = +32
    const int kq8 = (tid & 7) ^ (sr8 & 7);          // swizzled source k-chunk
    const ushort_t* gAh = Xh + (size_t)(row0 + sr8) * HDIM + kq8 * 8;
    const ushort_t* gAm = Xm + (size_t)(row0 + sr8) * HDIM + kq8 * 8;
    const ushort_t* gBh = XTh + (size_t)(col0 + sr8) * HDIM + kq8 * 8;
    const ushort_t* gBm = XTm + (size_t)(col0 + sr8) * HDIM + kq8 * 8;
    const size_t p1 = (size_t)32 * HDIM;            // pass-1 global offset

    const int j0 = (quad ^ (li & 7)) * 8;
    const int aoff = (w * 16 + li) * 64 + j0;
    const int b0o = (0 * 16 + li) * 64 + j0;
    const int b1o = (1 * 16 + li) * 64 + j0;
    const int b2o = (2 * 16 + li) * 64 + j0;
    const int b3o = (3 * 16 + li) * 64 + j0;

    {
      ushort_t* lb = lwb;
      gload16(gAh, lb);              gload16(gAh + p1, lb + 2048);
      gload16(gAm, lb + SLAB);       gload16(gAm + p1, lb + SLAB + 2048);
      gload16(gBh, lb + BBASE);      gload16(gBh + p1, lb + BBASE + 2048);
      gload16(gBm, lb + BBASE + SLAB); gload16(gBm + p1, lb + BBASE + SLAB + 2048);
    }
    __syncthreads();

    int cur = 0;
    for (int k0 = 0; k0 < HDIM; k0 += 64) {
      if (k0 + 64 < HDIM) {
        ushort_t* lb = lwb + (cur ^ 1) * BUFSTR;
        const int kn = k0 + 64;
        gload16(gAh + kn, lb);              gload16(gAh + p1 + kn, lb + 2048);
        gload16(gAm + kn, lb + SLAB);       gload16(gAm + p1 + kn, lb + SLAB + 2048);
        gload16(gBh + kn, lb + BBASE);      gload16(gBh + p1 + kn, lb + BBASE + 2048);
        gload16(gBm + kn, lb + BBASE + SLAB); gload16(gBm + p1 + kn, lb + BBASE + SLAB + 2048);
      }
      const int cb = cur * BUFSTR;
#pragma unroll
      for (int cc = 0; cc < 2; ++cc) {
        const int cx = cc * 32;  // elem-offset XOR for k-half
        bf16x8 ah = *(const bf16x8*)&sm[cb + (aoff ^ cx)];
        bf16x8 am = *(const bf16x8*)&sm[cb + SLAB + (aoff ^ cx)];
        {
          bf16x8 bh = *(const bf16x8*)&sm[cb + BBASE + (b0o ^ cx)];
          bf16x8 bm = *(const bf16x8*)&sm[cb + BBASE + SLAB + (b0o ^ cx)];
          acc0 = __builtin_amdgcn_mfma_f32_16x16x32_bf16(ah, bh, acc0, 0, 0, 0);
          acc0 = __builtin_amdgcn_mfma_f32_16x16x32_bf16(ah, bm, acc0, 0, 0, 0);
          acc0 = __builtin_amdgcn_mfma_f32_16x16x32_bf16(am, bh, acc0, 0, 0, 0);
          acc0 = __builtin_amdgcn_mfma_f32_16x16x32_bf16(am, bm, acc0, 0, 0, 0);
        }
        {
          bf16x8 bh = *(const bf16x8*)&sm[cb + BBASE + (b1o ^ cx)];
          bf16x8 bm = *(const bf16x8*)&sm[cb + BBASE + SLAB + (b1o ^ cx)];
          acc1 = __builtin_amdgcn_mfma_f32_16x16x32_bf16(ah, bh, acc1, 0, 0, 0);
          acc1 = __builtin_amdgcn_mfma_f32_16x16x32_bf16(ah, bm, acc1, 0, 0, 0);
          acc1 = __builtin_amdgcn_mfma_f32_16x16x32_bf16(am, bh, acc1, 0, 0, 0);
          acc1 = __builtin_amdgcn_mfma_f32_16x16x32_bf16(am, bm, acc1, 0, 0, 0);
        }
        {
          bf16x8 bh = *(const bf16x8*)&sm[cb + BBASE + (b2o ^ cx)];
          bf16x8 bm = *(const bf16x8*)&sm[cb + BBASE + SLAB + (b2o ^ cx)];
          acc2 = __builtin_amdgcn_mfma_f32_16x16x32_bf16(ah, bh, acc2, 0, 0, 0);
          acc2 = __builtin_amdgcn_mfma_f32_16x16x32_bf16(ah, bm, acc2, 0, 0, 0);
          acc2 = __builtin_amdgcn_mfma_f32_16x16x32_bf16(am, bh, acc2, 0, 0, 0);
          acc2 = __builtin_amdgcn_mfma_f32_16x16x32_bf16(am, bm, acc2, 0, 0, 0);
        }
        {
          bf16x8 bh = *(const bf16x8*)&sm[cb + BBASE + (b3o ^ cx)];
          bf16x8 bm = *(const bf16x8*)&sm[cb + BBASE + SLAB + (b3o ^ cx)];
          acc3 = __builtin_amdgcn_mfma_f32_16x16x32_bf16(ah, bh, acc3, 0, 0, 0);
          acc3 = __builtin_amdgcn_mfma_f32_16x16x32_bf16(ah, bm, acc3, 0, 0, 0);
          acc3 = __builtin_amdgcn_mfma_f32_16x16x32_bf16(am, bh, acc3, 0, 0, 0);
          acc3 = __builtin_amdgcn_mfma_f32_16x16x32_bf16(am, bm, acc3, 0, 0, 0);
        }
      }
      __syncthreads();
      cur ^= 1;
    }
  }

  // ---- epilogue: split, store row-major + LDS-transposed splits ----
  floatx4 accs[4] = {acc0, acc1, acc2, acc3};
#pragma unroll
  for (int j = 0; j < 4; ++j) {
#pragma unroll
    for (int e = 0; e < 4; ++e) {
      float z = accs[j][e];
      int rl = w * 16 + quad * 4 + e;
      int cl = j * 16 + li;
      size_t go = (size_t)(row0 + rl) * HDIM + col0 + cl;
      ushort_t h = f2bf(z); float r1 = z - bf2f(h);
      ushort_t mq = f2bf(r1);
      if (WROW) { Zh[go] = h; Zm[go] = mq; }
      sm[0 * 64 * TSTR + rl * TSTR + cl] = h;
      sm[1 * 64 * TSTR + rl * TSTR + cl] = mq;
      if (WRITEL) {
        ushort_t lq = f2bf(r1 - bf2f(mq));
        if (WROW) Zl[go] = lq;
        sm[2 * 64 * TSTR + rl * TSTR + cl] = lq;
      }
    }
  }
  __syncthreads();
  const int c = tid >> 2, q2 = tid & 3;
  ushort_t* dsts[3] = {ZTh, ZTm, ZTl};
  const int npass = WRITEL ? 3 : 2;
#pragma unroll
  for (int s = 0; s < 3; ++s) {
    if (s >= npass) break;
    ushort_t tmp[16];
#pragma unroll
    for (int rr = 0; rr < 16; ++rr) tmp[rr] = sm[s * 64 * TSTR + (q2 * 16 + rr) * TSTR + c];
    size_t gt = (size_t)(col0 + c) * HDIM + row0 + q2 * 16;
    *(uint4*)&dsts[s][gt] = ((uint4*)tmp)[0];
    *(uint4*)&dsts[s][gt + 8] = ((uint4*)tmp)[1];
  }
}

// ---------------- U rows 16..31 = rows 0..15 x A^1024 (PT = A^1024 transposed splits) ----------------
__global__ __launch_bounds__(256) void utail16(const ushort_t* __restrict__ PTh,
                                               const ushort_t* __restrict__ PTm,
                                               float* __restrict__ U) {
  const int wv = blockIdx.x * 4 + (threadIdx.x >> 6);
  const int lane = threadIdx.x & 63;
  float acc[16];
#pragma unroll
  for (int m = 0; m < 16; ++m) acc[m] = 0.f;
  for (int k = lane; k < HDIM; k += 64) {
    float a = bf2f(PTh[(size_t)wv * HDIM + k]) + bf2f(PTm[(size_t)wv * HDIM + k]);
#pragma unroll
    for (int m = 0; m < 16; ++m) acc[m] += a * U[(size_t)m * HDIM + k];
  }
#pragma unroll
  for (int m = 0; m < 16; ++m) {
    float s = acc[m];
    for (int off = 32; off; off >>= 1) s += __shfl_down(s, off);
    if (lane == 0) U[(size_t)(16 + m) * HDIM + wv] = s;
  }
}

// ---------------- K[m] = U row (m>>6) . V col (m&63) ----------------
__global__ __launch_bounds__(256) void wavedotK(const float* __restrict__ U,
                                                const float* __restrict__ Vc,
                                                float* __restrict__ Km) {
  int wv = (blockIdx.x * blockDim.x + threadIdx.x) >> 6;
  int lane = threadIdx.x & 63;
  if (wv >= 32 * 64) return;
  int mr = wv >> 6;
  int nc = wv & 63;
  float s = 0.f;
  for (int k = lane; k < HDIM; k += 64) s += U[mr * HDIM + k] * Vc[nc * HDIM + k];
  for (int off = 32; off; off >>= 1) s += __shfl_down(s, off);
  if (lane == 0) Km[wv] = s;
}

// ---------------- causal conv, LDS-tiled, 4-way split accumulator ----------------
__global__ __launch_bounds__(256) void convk2(const float* __restrict__ u,
                                              const float* __restrict__ Km,
                                              const float* __restrict__ Dv,
                                              float* __restrict__ y) {
  __shared__ float ks[256];
  __shared__ float us[512];
  const int tt = threadIdx.x;
  const int t0 = blockIdx.x * 256;
  const int b = blockIdx.y;
  const float* ub = u + (size_t)b * TLEN;
  const int t = t0 + tt;
  float s0 = Dv[0] * ub[t], s1 = 0.f, s2 = 0.f, s3 = 0.f;
  for (int mc = 0; mc <= t0; mc += 256) {
    __syncthreads();
    ks[tt] = Km[mc + tt];
    int w0 = t0 - mc - 255;
    int g0 = w0 + tt;
    us[tt] = (g0 >= 0) ? ub[g0] : 0.f;
    int g1 = w0 + 256 + tt;
    us[256 + tt] = (g1 < TLEN) ? ub[g1] : 0.f;
    __syncthreads();
    if (mc < t0) {
#pragma unroll 4
      for (int r = 0; r < 256; r += 4) {
        float4 kv = *(const float4*)&ks[r];
        s0 += kv.x * us[tt - r + 255];
        s1 += kv.y * us[tt - r + 254];
        s2 += kv.z * us[tt - r + 253];
        s3 += kv.w * us[tt - r + 252];
      }
    } else {
      for (int r = 0; r <= tt; ++r) s0 += ks[r] * us[tt - r + 255];
    }
  }
  y[(size_t)b * TLEN + t] = s0 + s1 + s2 + s3;
}

extern "C" void kernel_launch(void* const* d_in, const int* in_sizes, int n_in,
                              void* d_out, int out_size, void* d_ws, size_t ws_size,
                              hipStream_t stream) {
  const float* u  = (const float*)d_in[0];
  const float* A  = (const float*)d_in[1];
  const float* Bv = (const float*)d_in[2];
  const float* Cv = (const float*)d_in[3];
  const float* Dv = (const float*)d_in[4];
  float* out = (float*)d_out;

  char* wsb = (char*)d_ws;
  size_t off = 0;
  ushort_t* S[2][6];
  for (int s = 0; s < 2; ++s)
    for (int a = 0; a < 6; ++a) { S[s][a] = (ushort_t*)(wsb + off); off += (size_t)2 << 20; }
  float* Vc = (float*)(wsb + off); off += 64 * HDIM * 4;
  float* U  = (float*)(wsb + off); off += 32 * HDIM * 4;
  float* Km = (float*)(wsb + off); off += TLEN * 4;

  const dim3 gsq(512);  // 256 squaring blocks (swizzled) + 256 tail blocks

#define SQ(MODE, NC, SIX, WRL, WROW, IN, OUT, VU)                              \
  sq_mfma<MODE, NC, SIX, WRL, WROW><<<gsq, 256, 0, stream>>>(                  \
      S[IN][0], S[IN][1], S[IN][2], S[IN][3], S[IN][4], S[IN][5],              \
      S[OUT][0], S[OUT][1], S[OUT][2], S[OUT][3], S[OUT][4], S[OUT][5],        \
      A, Bv, VU)

  prep<<<dim3(264), 256, 0, stream>>>(A, Bv, Cv,
      S[0][0], S[0][1], S[0][2], S[0][3], S[0][4], S[0][5], Vc, U);

  SQ(0, 1,  true,  true,  true,  0, 1, Vc);  // A^2    ; tail: V col1 = A*Bv
  SQ(1, 2,  true,  true,  true,  1, 0, Vc);  // A^4    ; tail: V cols 2,3    (A^2)
  SQ(1, 4,  true,  true,  true,  0, 1, Vc);  // A^8    ; tail: V cols 4..7   (A^4)
  SQ(1, 8,  true,  false, true,  1, 0, Vc);  // A^16   ; tail: V cols 8..15  (A^8)
  SQ(1, 16, false, false, true,  0, 1, Vc);  // A^32   ; tail: V cols 16..31 (A^16)
  SQ(1, 32, false, false, true,  1, 0, Vc);  // A^64   ; tail: V cols 32..63 (A^32)
  SQ(2, 1,  false, false, true,  0, 1, U);   // A^128  ; tail: U row 1       (A^64)
  SQ(2, 2,  false, false, true,  1, 0, U);   // A^256  ; tail: U rows 2,3    (A^128)
  SQ(2, 4,  false, false, true,  0, 1, U);   // A^512  ; tail: U rows 4..7   (A^256); WROW: sq10 input
  SQ(2, 8,  false, false, false, 1, 0, U);   // A^1024 T-splits only; tail: U rows 8..15 (A^512)
#undef SQ

  // U rows 16..31 via A^1024 (S[0] transposed splits)
  utail16<<<dim3(256), 256, 0, stream>>>(S[0][3], S[0][4], U);

  wavedotK<<<dim3(512), 256, 0, stream>>>(U, Vc, Km);
  convk2<<<dim3(TLEN / 256, NBATCH), 256, 0, stream>>>(u, Km, Dv, out);
}

// Round 8
// 400.994 us; speedup vs baseline: 1.0165x; 1.0165x over previous
//
#include <hip/hip_runtime.h>

#define HDIM 1024
#define TLEN 2048
#define NBATCH 16

typedef short bf16x8 __attribute__((ext_vector_type(8)));
typedef float floatx4 __attribute__((ext_vector_type(4)));
typedef unsigned short ushort_t;

__device__ __forceinline__ ushort_t f2bf(float x) {
  unsigned u = __float_as_uint(x);
  unsigned r = (u + 0x7FFFu + ((u >> 16) & 1u)) >> 16;
  return (ushort_t)r;
}
__device__ __forceinline__ float bf2f(ushort_t h) {
  return __uint_as_float(((unsigned)h) << 16);
}

// async global->LDS, 16B per lane; LDS dest = wave-uniform base + lane*16 (linear)
typedef __attribute__((address_space(1))) void gvoid_t;
typedef __attribute__((address_space(3))) void lvoid_t;
__device__ __forceinline__ void gload16(const ushort_t* g, ushort_t* l) {
  __builtin_amdgcn_global_load_lds((gvoid_t*)g, (lvoid_t*)l, 16, 0, 0);
}

#define TSTR 71  // transpose stride (64x64 tiles)

// ---------------- prep: split A into bf16 h/m/l (+transposed); init V col0 / U row0 ----------------
__global__ __launch_bounds__(256) void prep(const float* __restrict__ A,
    const float* __restrict__ Bv, const float* __restrict__ Cv,
    ushort_t* __restrict__ Ah, ushort_t* __restrict__ Am, ushort_t* __restrict__ Al,
    ushort_t* __restrict__ ATh, ushort_t* __restrict__ ATm, ushort_t* __restrict__ ATl,
    float* __restrict__ Vc, float* __restrict__ U) {
  __shared__ ushort_t Lt[3 * 64 * TSTR];
  const int tid = threadIdx.x;
  if (blockIdx.x >= 256) {  // init blocks
    int i = (blockIdx.x - 256) * 256 + tid;
    if (i < HDIM) Vc[i] = Bv[i];
    else U[i - HDIM] = Cv[i - HDIM];
    return;
  }
  const int row0 = (blockIdx.x >> 4) * 64, col0 = (blockIdx.x & 15) * 64;
  const int r = tid >> 2, q = tid & 3;
  ushort_t hs[16], ms[16], ls[16];
#pragma unroll
  for (int c4 = 0; c4 < 4; ++c4) {
    float4 a = *(const float4*)&A[(row0 + r) * HDIM + col0 + q * 16 + c4 * 4];
    float av[4] = {a.x, a.y, a.z, a.w};
#pragma unroll
    for (int i = 0; i < 4; ++i) {
      float z = av[i];
      ushort_t h = f2bf(z); float r1 = z - bf2f(h);
      ushort_t mq = f2bf(r1); float r2 = r1 - bf2f(mq);
      ushort_t lq = f2bf(r2);
      hs[c4 * 4 + i] = h; ms[c4 * 4 + i] = mq; ls[c4 * 4 + i] = lq;
    }
  }
  size_t go = (size_t)(row0 + r) * HDIM + col0 + q * 16;
  *(uint4*)&Ah[go] = ((uint4*)hs)[0]; *(uint4*)&Ah[go + 8] = ((uint4*)hs)[1];
  *(uint4*)&Am[go] = ((uint4*)ms)[0]; *(uint4*)&Am[go + 8] = ((uint4*)ms)[1];
  *(uint4*)&Al[go] = ((uint4*)ls)[0]; *(uint4*)&Al[go + 8] = ((uint4*)ls)[1];
#pragma unroll
  for (int i = 0; i < 16; ++i) {
    int c = q * 16 + i;
    Lt[0 * 64 * TSTR + r * TSTR + c] = hs[i];
    Lt[1 * 64 * TSTR + r * TSTR + c] = ms[i];
    Lt[2 * 64 * TSTR + r * TSTR + c] = ls[i];
  }
  __syncthreads();
  const int c = tid >> 2, q2 = tid & 3;
  ushort_t* dsts[3] = {ATh, ATm, ATl};
#pragma unroll
  for (int s = 0; s < 3; ++s) {
    ushort_t tmp[16];
#pragma unroll
    for (int rr = 0; rr < 16; ++rr) tmp[rr] = Lt[s * 64 * TSTR + (q2 * 16 + rr) * TSTR + c];
    size_t gt = (size_t)(col0 + c) * HDIM + row0 + q2 * 16;
    *(uint4*)&dsts[s][gt] = ((uint4*)tmp)[0];
    *(uint4*)&dsts[s][gt + 8] = ((uint4*)tmp)[1];
  }
}

// ---------------- Z = X*X, 64x64 tiles (256 blocks, XCD-swizzled) + fused V/U tail ----------------
// SIX (sq1..4): BK=32 path.  FOUR (sq5..9): BK=64 path (swizzled slots, 16 barriers).
// Tails: DIRECT streaming — no LDS staging/barriers; latency hidden by unrolled k-loop + waves.
template <int MODE, int NC, bool SIX, bool WRITEL, bool WROW>
__global__ __launch_bounds__(256) void sq_mfma(
    const ushort_t* __restrict__ Xh, const ushort_t* __restrict__ Xm,
    const ushort_t* __restrict__ Xl,
    const ushort_t* __restrict__ XTh, const ushort_t* __restrict__ XTm,
    const ushort_t* __restrict__ XTl,
    ushort_t* __restrict__ Zh, ushort_t* __restrict__ Zm, ushort_t* __restrict__ Zl,
    ushort_t* __restrict__ ZTh, ushort_t* __restrict__ ZTm, ushort_t* __restrict__ ZTl,
    const float* __restrict__ Af, const float* __restrict__ Bvf,
    float* __restrict__ VU) {
  constexpr int BK = SIX ? 32 : 64;
  constexpr int SLAB = 64 * BK;                 // elems per array per K-step buffer
  constexpr int BUFSTR = (SIX ? 6 : 4) * SLAB;
  constexpr int BBASE = (SIX ? 3 : 2) * SLAB;   // B-side slabs start here
  constexpr int LDS_ELEMS = 2 * BUFSTR;         // SIX: 48 KB, FOUR: 64 KB
  __shared__ __align__(16) ushort_t sm[LDS_ELEMS];
  const int tid = threadIdx.x;

  if (blockIdx.x >= 256) {  // ---- tail blocks: 256 blocks -> 1024 waves ----
    const int tb = blockIdx.x - 256;
    const int wv = tb * 4 + (tid >> 6);
    const int lane = tid & 63;
    if (MODE == 0) {
      float acc = 0.f;
      for (int k = lane; k < HDIM; k += 64) acc += Af[(size_t)wv * HDIM + k] * Bvf[k];
      for (int off = 32; off; off >>= 1) acc += __shfl_down(acc, off);
      if (lane == 0) VU[HDIM + wv] = acc;
    } else {
      const ushort_t* Ph = (MODE == 1) ? Xh : XTh;
      const ushort_t* Pm = (MODE == 1) ? Xm : XTm;
      float acc[NC];
#pragma unroll
      for (int n = 0; n < NC; ++n) acc[n] = 0.f;
      for (int k = lane; k < HDIM; k += 64) {
        float a = bf2f(Ph[(size_t)wv * HDIM + k]) + bf2f(Pm[(size_t)wv * HDIM + k]);
#pragma unroll
        for (int n = 0; n < NC; ++n) acc[n] += a * VU[(size_t)n * HDIM + k];
      }
#pragma unroll
      for (int n = 0; n < NC; ++n) {
        float s = acc[n];
        for (int off = 32; off; off >>= 1) s += __shfl_down(s, off);
        if (lane == 0) VU[(size_t)(NC + n) * HDIM + wv] = s;
      }
    }
    return;
  }

  // ---- squaring blocks: 16x16 grid of 64x64 tiles, XCD-rectangle swizzle ----
  const int bb = blockIdx.x;
  const int xcd = bb & 7, slot = bb >> 3;
  const int tr = 4 * (xcd >> 1) + (slot >> 3);
  const int tc = 8 * (xcd & 1) + (slot & 7);
  const int row0 = tr * 64, col0 = tc * 64;

  const int w = tid >> 6, l = tid & 63, li = l & 15, quad = l >> 4;

  floatx4 acc0 = {0.f, 0.f, 0.f, 0.f}, acc1 = acc0, acc2 = acc0, acc3 = acc0;

  ushort_t* lwb = &sm[w * 512];  // per-wave uniform LDS base (pass 0)

  if (SIX) {
    // ================= BK=32 path =================
    const int sr = tid >> 2, sq4 = tid & 3;
    const int aoff = (w * 16 + li) * 32 + quad * 8;
    const int b0o = (0 * 16 + li) * 32 + quad * 8;
    const int b1o = (1 * 16 + li) * 32 + quad * 8;
    const int b2o = (2 * 16 + li) * 32 + quad * 8;
    const int b3o = (3 * 16 + li) * 32 + quad * 8;

    const ushort_t* gAh = Xh + (size_t)(row0 + sr) * HDIM + sq4 * 8;
    const ushort_t* gAm = Xm + (size_t)(row0 + sr) * HDIM + sq4 * 8;
    const ushort_t* gAl = Xl + (size_t)(row0 + sr) * HDIM + sq4 * 8;
    const ushort_t* gBh = XTh + (size_t)(col0 + sr) * HDIM + sq4 * 8;
    const ushort_t* gBm = XTm + (size_t)(col0 + sr) * HDIM + sq4 * 8;
    const ushort_t* gBl = XTl + (size_t)(col0 + sr) * HDIM + sq4 * 8;

    {
      ushort_t* lb = lwb;
      gload16(gAh, lb);
      gload16(gAm, lb + SLAB);
      gload16(gAl, lb + 2 * SLAB);
      gload16(gBh, lb + BBASE);
      gload16(gBm, lb + BBASE + SLAB);
      gload16(gBl, lb + BBASE + 2 * SLAB);
    }
    __syncthreads();

    int cur = 0;
    for (int k0 = 0; k0 < HDIM; k0 += 32) {
      if (k0 + 32 < HDIM) {
        ushort_t* lb = lwb + (cur ^ 1) * BUFSTR;
        const int kn = k0 + 32;
        gload16(gAh + kn, lb);
        gload16(gAm + kn, lb + SLAB);
        gload16(gAl + kn, lb + 2 * SLAB);
        gload16(gBh + kn, lb + BBASE);
        gload16(gBm + kn, lb + BBASE + SLAB);
        gload16(gBl + kn, lb + BBASE + 2 * SLAB);
      }
      const int cb = cur * BUFSTR;
      bf16x8 ah = *(const bf16x8*)&sm[cb + aoff];
      bf16x8 am = *(const bf16x8*)&sm[cb + SLAB + aoff];
      bf16x8 al = *(const bf16x8*)&sm[cb + 2 * SLAB + aoff];
      {
        bf16x8 bh = *(const bf16x8*)&sm[cb + BBASE + b0o];
        bf16x8 bm = *(const bf16x8*)&sm[cb + BBASE + SLAB + b0o];
        bf16x8 bl = *(const bf16x8*)&sm[cb + BBASE + 2 * SLAB + b0o];
        acc0 = __builtin_amdgcn_mfma_f32_16x16x32_bf16(ah, bh, acc0, 0, 0, 0);
        acc0 = __builtin_amdgcn_mfma_f32_16x16x32_bf16(ah, bm, acc0, 0, 0, 0);
        acc0 = __builtin_amdgcn_mfma_f32_16x16x32_bf16(am, bh, acc0, 0, 0, 0);
        acc0 = __builtin_amdgcn_mfma_f32_16x16x32_bf16(am, bm, acc0, 0, 0, 0);
        acc0 = __builtin_amdgcn_mfma_f32_16x16x32_bf16(ah, bl, acc0, 0, 0, 0);
        acc0 = __builtin_amdgcn_mfma_f32_16x16x32_bf16(al, bh, acc0, 0, 0, 0);
      }
      {
        bf16x8 bh = *(const bf16x8*)&sm[cb + BBASE + b1o];
        bf16x8 bm = *(const bf16x8*)&sm[cb + BBASE + SLAB + b1o];
        bf16x8 bl = *(const bf16x8*)&sm[cb + BBASE + 2 * SLAB + b1o];
        acc1 = __builtin_amdgcn_mfma_f32_16x16x32_bf16(ah, bh, acc1, 0, 0, 0);
        acc1 = __builtin_amdgcn_mfma_f32_16x16x32_bf16(ah, bm, acc1, 0, 0, 0);
        acc1 = __builtin_amdgcn_mfma_f32_16x16x32_bf16(am, bh, acc1, 0, 0, 0);
        acc1 = __builtin_amdgcn_mfma_f32_16x16x32_bf16(am, bm, acc1, 0, 0, 0);
        acc1 = __builtin_amdgcn_mfma_f32_16x16x32_bf16(ah, bl, acc1, 0, 0, 0);
        acc1 = __builtin_amdgcn_mfma_f32_16x16x32_bf16(al, bh, acc1, 0, 0, 0);
      }
      {
        bf16x8 bh = *(const bf16x8*)&sm[cb + BBASE + b2o];
        bf16x8 bm = *(const bf16x8*)&sm[cb + BBASE + SLAB + b2o];
        bf16x8 bl = *(const bf16x8*)&sm[cb + BBASE + 2 * SLAB + b2o];
        acc2 = __builtin_amdgcn_mfma_f32_16x16x32_bf16(ah, bh, acc2, 0, 0, 0);
        acc2 = __builtin_amdgcn_mfma_f32_16x16x32_bf16(ah, bm, acc2, 0, 0, 0);
        acc2 = __builtin_amdgcn_mfma_f32_16x16x32_bf16(am, bh, acc2, 0, 0, 0);
        acc2 = __builtin_amdgcn_mfma_f32_16x16x32_bf16(am, bm, acc2, 0, 0, 0);
        acc2 = __builtin_amdgcn_mfma_f32_16x16x32_bf16(ah, bl, acc2, 0, 0, 0);
        acc2 = __builtin_amdgcn_mfma_f32_16x16x32_bf16(al, bh, acc2, 0, 0, 0);
      }
      {
        bf16x8 bh = *(const bf16x8*)&sm[cb + BBASE + b3o];
        bf16x8 bm = *(const bf16x8*)&sm[cb + BBASE + SLAB + b3o];
        bf16x8 bl = *(const bf16x8*)&sm[cb + BBASE + 2 * SLAB + b3o];
        acc3 = __builtin_amdgcn_mfma_f32_16x16x32_bf16(ah, bh, acc3, 0, 0, 0);
        acc3 = __builtin_amdgcn_mfma_f32_16x16x32_bf16(ah, bm, acc3, 0, 0, 0);
        acc3 = __builtin_amdgcn_mfma_f32_16x16x32_bf16(am, bh, acc3, 0, 0, 0);
        acc3 = __builtin_amdgcn_mfma_f32_16x16x32_bf16(am, bm, acc3, 0, 0, 0);
        acc3 = __builtin_amdgcn_mfma_f32_16x16x32_bf16(ah, bl, acc3, 0, 0, 0);
        acc3 = __builtin_amdgcn_mfma_f32_16x16x32_bf16(al, bh, acc3, 0, 0, 0);
      }
      __syncthreads();
      cur ^= 1;
    }
  } else {
    // ================= BK=64 path (swizzled slots, 16 barriers) =================
    const int sr8 = tid >> 3;                       // row 0..31 (pass 0); pass 1 = +32
    const int kq8 = (tid & 7) ^ (sr8 & 7);          // swizzled source k-chunk
    const ushort_t* gAh = Xh + (size_t)(row0 + sr8) * HDIM + kq8 * 8;
    const ushort_t* gAm = Xm + (size_t)(row0 + sr8) * HDIM + kq8 * 8;
    const ushort_t* gBh = XTh + (size_t)(col0 + sr8) * HDIM + kq8 * 8;
    const ushort_t* gBm = XTm + (size_t)(col0 + sr8) * HDIM + kq8 * 8;
    const size_t p1 = (size_t)32 * HDIM;            // pass-1 global offset

    const int j0 = (quad ^ (li & 7)) * 8;
    const int aoff = (w * 16 + li) * 64 + j0;
    const int b0o = (0 * 16 + li) * 64 + j0;
    const int b1o = (1 * 16 + li) * 64 + j0;
    const int b2o = (2 * 16 + li) * 64 + j0;
    const int b3o = (3 * 16 + li) * 64 + j0;

    {
      ushort_t* lb = lwb;
      gload16(gAh, lb);              gload16(gAh + p1, lb + 2048);
      gload16(gAm, lb + SLAB);       gload16(gAm + p1, lb + SLAB + 2048);
      gload16(gBh, lb + BBASE);      gload16(gBh + p1, lb + BBASE + 2048);
      gload16(gBm, lb + BBASE + SLAB); gload16(gBm + p1, lb + BBASE + SLAB + 2048);
    }
    __syncthreads();

    int cur = 0;
    for (int k0 = 0; k0 < HDIM; k0 += 64) {
      if (k0 + 64 < HDIM) {
        ushort_t* lb = lwb + (cur ^ 1) * BUFSTR;
        const int kn = k0 + 64;
        gload16(gAh + kn, lb);              gload16(gAh + p1 + kn, lb + 2048);
        gload16(gAm + kn, lb + SLAB);       gload16(gAm + p1 + kn, lb + SLAB + 2048);
        gload16(gBh + kn, lb + BBASE);      gload16(gBh + p1 + kn, lb + BBASE + 2048);
        gload16(gBm + kn, lb + BBASE + SLAB); gload16(gBm + p1 + kn, lb + BBASE + SLAB + 2048);
      }
      const int cb = cur * BUFSTR;
#pragma unroll
      for (int cc = 0; cc < 2; ++cc) {
        const int cx = cc * 32;  // elem-offset XOR for k-half
        bf16x8 ah = *(const bf16x8*)&sm[cb + (aoff ^ cx)];
        bf16x8 am = *(const bf16x8*)&sm[cb + SLAB + (aoff ^ cx)];
        {
          bf16x8 bh = *(const bf16x8*)&sm[cb + BBASE + (b0o ^ cx)];
          bf16x8 bm = *(const bf16x8*)&sm[cb + BBASE + SLAB + (b0o ^ cx)];
          acc0 = __builtin_amdgcn_mfma_f32_16x16x32_bf16(ah, bh, acc0, 0, 0, 0);
          acc0 = __builtin_amdgcn_mfma_f32_16x16x32_bf16(ah, bm, acc0, 0, 0, 0);
          acc0 = __builtin_amdgcn_mfma_f32_16x16x32_bf16(am, bh, acc0, 0, 0, 0);
          acc0 = __builtin_amdgcn_mfma_f32_16x16x32_bf16(am, bm, acc0, 0, 0, 0);
        }
        {
          bf16x8 bh = *(const bf16x8*)&sm[cb + BBASE + (b1o ^ cx)];
          bf16x8 bm = *(const bf16x8*)&sm[cb + BBASE + SLAB + (b1o ^ cx)];
          acc1 = __builtin_amdgcn_mfma_f32_16x16x32_bf16(ah, bh, acc1, 0, 0, 0);
          acc1 = __builtin_amdgcn_mfma_f32_16x16x32_bf16(ah, bm, acc1, 0, 0, 0);
          acc1 = __builtin_amdgcn_mfma_f32_16x16x32_bf16(am, bh, acc1, 0, 0, 0);
          acc1 = __builtin_amdgcn_mfma_f32_16x16x32_bf16(am, bm, acc1, 0, 0, 0);
        }
        {
          bf16x8 bh = *(const bf16x8*)&sm[cb + BBASE + (b2o ^ cx)];
          bf16x8 bm = *(const bf16x8*)&sm[cb + BBASE + SLAB + (b2o ^ cx)];
          acc2 = __builtin_amdgcn_mfma_f32_16x16x32_bf16(ah, bh, acc2, 0, 0, 0);
          acc2 = __builtin_amdgcn_mfma_f32_16x16x32_bf16(ah, bm, acc2, 0, 0, 0);
          acc2 = __builtin_amdgcn_mfma_f32_16x16x32_bf16(am, bh, acc2, 0, 0, 0);
          acc2 = __builtin_amdgcn_mfma_f32_16x16x32_bf16(am, bm, acc2, 0, 0, 0);
        }
        {
          bf16x8 bh = *(const bf16x8*)&sm[cb + BBASE + (b3o ^ cx)];
          bf16x8 bm = *(const bf16x8*)&sm[cb + BBASE + SLAB + (b3o ^ cx)];
          acc3 = __builtin_amdgcn_mfma_f32_16x16x32_bf16(ah, bh, acc3, 0, 0, 0);
          acc3 = __builtin_amdgcn_mfma_f32_16x16x32_bf16(ah, bm, acc3, 0, 0, 0);
          acc3 = __builtin_amdgcn_mfma_f32_16x16x32_bf16(am, bh, acc3, 0, 0, 0);
          acc3 = __builtin_amdgcn_mfma_f32_16x16x32_bf16(am, bm, acc3, 0, 0, 0);
        }
      }
      __syncthreads();
      cur ^= 1;
    }
  }

  // ---- epilogue: split, store row-major + LDS-transposed splits ----
  floatx4 accs[4] = {acc0, acc1, acc2, acc3};
#pragma unroll
  for (int j = 0; j < 4; ++j) {
#pragma unroll
    for (int e = 0; e < 4; ++e) {
      float z = accs[j][e];
      int rl = w * 16 + quad * 4 + e;
      int cl = j * 16 + li;
      size_t go = (size_t)(row0 + rl) * HDIM + col0 + cl;
      ushort_t h = f2bf(z); float r1 = z - bf2f(h);
      ushort_t mq = f2bf(r1);
      if (WROW) { Zh[go] = h; Zm[go] = mq; }
      sm[0 * 64 * TSTR + rl * TSTR + cl] = h;
      sm[1 * 64 * TSTR + rl * TSTR + cl] = mq;
      if (WRITEL) {
        ushort_t lq = f2bf(r1 - bf2f(mq));
        if (WROW) Zl[go] = lq;
        sm[2 * 64 * TSTR + rl * TSTR + cl] = lq;
      }
    }
  }
  __syncthreads();
  const int c = tid >> 2, q2 = tid & 3;
  ushort_t* dsts[3] = {ZTh, ZTm, ZTl};
  const int npass = WRITEL ? 3 : 2;
#pragma unroll
  for (int s = 0; s < 3; ++s) {
    if (s >= npass) break;
    ushort_t tmp[16];
#pragma unroll
    for (int rr = 0; rr < 16; ++rr) tmp[rr] = sm[s * 64 * TSTR + (q2 * 16 + rr) * TSTR + c];
    size_t gt = (size_t)(col0 + c) * HDIM + row0 + q2 * 16;
    *(uint4*)&dsts[s][gt] = ((uint4*)tmp)[0];
    *(uint4*)&dsts[s][gt + 8] = ((uint4*)tmp)[1];
  }
}

// ---------------- U extension: rows dst..dst+7 = rows dst-8..dst-1 x A^512 ----------------
__global__ __launch_bounds__(256) void utail8(const ushort_t* __restrict__ PTh,
                                              const ushort_t* __restrict__ PTm,
                                              float* __restrict__ U, int dstbase) {
  const int wv = blockIdx.x * 4 + (threadIdx.x >> 6);
  const int lane = threadIdx.x & 63;
  float acc[8];
#pragma unroll
  for (int m = 0; m < 8; ++m) acc[m] = 0.f;
  const float* Usrc = U + (size_t)(dstbase - 8) * HDIM;
  for (int k = lane; k < HDIM; k += 64) {
    float a = bf2f(PTh[(size_t)wv * HDIM + k]) + bf2f(PTm[(size_t)wv * HDIM + k]);
#pragma unroll
    for (int m = 0; m < 8; ++m) acc[m] += a * Usrc[(size_t)m * HDIM + k];
  }
#pragma unroll
  for (int m = 0; m < 8; ++m) {
    float s = acc[m];
    for (int off = 32; off; off >>= 1) s += __shfl_down(s, off);
    if (lane == 0) U[(size_t)(dstbase + m) * HDIM + wv] = s;
  }
}

// ---------------- K[m] = U row (m>>6) . V col (m&63) ----------------
__global__ __launch_bounds__(256) void wavedotK(const float* __restrict__ U,
                                                const float* __restrict__ Vc,
                                                float* __restrict__ Km) {
  int wv = (blockIdx.x * blockDim.x + threadIdx.x) >> 6;
  int lane = threadIdx.x & 63;
  if (wv >= 32 * 64) return;
  int mr = wv >> 6;
  int nc = wv & 63;
  float s = 0.f;
  for (int k = lane; k < HDIM; k += 64) s += U[mr * HDIM + k] * Vc[nc * HDIM + k];
  for (int off = 32; off; off >>= 1) s += __shfl_down(s, off);
  if (lane == 0) Km[wv] = s;
}

// ---------------- causal conv, LDS-tiled, 4-way split accumulator ----------------
__global__ __launch_bounds__(256) void convk2(const float* __restrict__ u,
                                              const float* __restrict__ Km,
                                              const float* __restrict__ Dv,
                                              float* __restrict__ y) {
  __shared__ float ks[256];
  __shared__ float us[512];
  const int tt = threadIdx.x;
  const int t0 = blockIdx.x * 256;
  const int b = blockIdx.y;
  const float* ub = u + (size_t)b * TLEN;
  const int t = t0 + tt;
  float s0 = Dv[0] * ub[t], s1 = 0.f, s2 = 0.f, s3 = 0.f;
  for (int mc = 0; mc <= t0; mc += 256) {
    __syncthreads();
    ks[tt] = Km[mc + tt];
    int w0 = t0 - mc - 255;
    int g0 = w0 + tt;
    us[tt] = (g0 >= 0) ? ub[g0] : 0.f;
    int g1 = w0 + 256 + tt;
    us[256 + tt] = (g1 < TLEN) ? ub[g1] : 0.f;
    __syncthreads();
    if (mc < t0) {
#pragma unroll 4
      for (int r = 0; r < 256; r += 4) {
        float4 kv = *(const float4*)&ks[r];
        s0 += kv.x * us[tt - r + 255];
        s1 += kv.y * us[tt - r + 254];
        s2 += kv.z * us[tt - r + 253];
        s3 += kv.w * us[tt - r + 252];
      }
    } else {
      for (int r = 0; r <= tt; ++r) s0 += ks[r] * us[tt - r + 255];
    }
  }
  y[(size_t)b * TLEN + t] = s0 + s1 + s2 + s3;
}

extern "C" void kernel_launch(void* const* d_in, const int* in_sizes, int n_in,
                              void* d_out, int out_size, void* d_ws, size_t ws_size,
                              hipStream_t stream) {
  const float* u  = (const float*)d_in[0];
  const float* A  = (const float*)d_in[1];
  const float* Bv = (const float*)d_in[2];
  const float* Cv = (const float*)d_in[3];
  const float* Dv = (const float*)d_in[4];
  float* out = (float*)d_out;

  char* wsb = (char*)d_ws;
  size_t off = 0;
  ushort_t* S[2][6];
  for (int s = 0; s < 2; ++s)
    for (int a = 0; a < 6; ++a) { S[s][a] = (ushort_t*)(wsb + off); off += (size_t)2 << 20; }
  float* Vc = (float*)(wsb + off); off += 64 * HDIM * 4;
  float* U  = (float*)(wsb + off); off += 32 * HDIM * 4;
  float* Km = (float*)(wsb + off); off += TLEN * 4;

  const dim3 gsq(512);  // 256 squaring blocks (swizzled) + 256 tail blocks

#define SQ(MODE, NC, SIX, WRL, WROW, IN, OUT, VU)                              \
  sq_mfma<MODE, NC, SIX, WRL, WROW><<<gsq, 256, 0, stream>>>(                  \
      S[IN][0], S[IN][1], S[IN][2], S[IN][3], S[IN][4], S[IN][5],              \
      S[OUT][0], S[OUT][1], S[OUT][2], S[OUT][3], S[OUT][4], S[OUT][5],        \
      A, Bv, VU)

  prep<<<dim3(264), 256, 0, stream>>>(A, Bv, Cv,
      S[0][0], S[0][1], S[0][2], S[0][3], S[0][4], S[0][5], Vc, U);

  SQ(0, 1,  true,  true,  true,  0, 1, Vc);  // A^2    ; tail: V col1 = A*Bv
  SQ(1, 2,  true,  true,  true,  1, 0, Vc);  // A^4    ; tail: V cols 2,3    (A^2)
  SQ(1, 4,  true,  true,  true,  0, 1, Vc);  // A^8    ; tail: V cols 4..7   (A^4)
  SQ(1, 8,  true,  false, true,  1, 0, Vc);  // A^16   ; tail: V cols 8..15  (A^8)
  SQ(1, 16, false, false, true,  0, 1, Vc);  // A^32   ; tail: V cols 16..31 (A^16)
  SQ(1, 32, false, false, true,  1, 0, Vc);  // A^64   ; tail: V cols 32..63 (A^32)
  SQ(2, 1,  false, false, true,  0, 1, U);   // A^128  ; tail: U row 1       (A^64)
  SQ(2, 2,  false, false, true,  1, 0, U);   // A^256  ; tail: U rows 2,3    (A^128)
  SQ(2, 4,  false, false, false, 0, 1, U);   // A^512  ; tail: U rows 4..7   (A^256); row-major unused
#undef SQ

  // U rows 8..31 via A^512 (S[1] transposed splits), sequential x3
  utail8<<<dim3(256), 256, 0, stream>>>(S[1][3], S[1][4], U, 8);
  utail8<<<dim3(256), 256, 0, stream>>>(S[1][3], S[1][4], U, 16);
  utail8<<<dim3(256), 256, 0, stream>>>(S[1][3], S[1][4], U, 24);

  wavedotK<<<dim3(512), 256, 0, stream>>>(U, Vc, Km);
  convk2<<<dim3(TLEN / 256, NBATCH), 256, 0, stream>>>(u, Km, Dv, out);
}

// Round 9
// 301.927 us; speedup vs baseline: 1.3500x; 1.3281x over previous
//
#include <hip/hip_runtime.h>

#define HDIM 1024
#define TLEN 2048
#define NBATCH 16

typedef short bf16x8 __attribute__((ext_vector_type(8)));
typedef float floatx4 __attribute__((ext_vector_type(4)));
typedef unsigned short ushort_t;

__device__ __forceinline__ ushort_t f2bf(float x) {
  unsigned u = __float_as_uint(x);
  unsigned r = (u + 0x7FFFu + ((u >> 16) & 1u)) >> 16;
  return (ushort_t)r;
}
__device__ __forceinline__ float bf2f(ushort_t h) {
  return __uint_as_float(((unsigned)h) << 16);
}

// async global->LDS, 16B per lane; LDS dest = wave-uniform base + lane*16 (linear)
typedef __attribute__((address_space(1))) void gvoid_t;
typedef __attribute__((address_space(3))) void lvoid_t;
__device__ __forceinline__ void gload16(const ushort_t* g, ushort_t* l) {
  __builtin_amdgcn_global_load_lds((gvoid_t*)g, (lvoid_t*)l, 16, 0, 0);
}

// counted vmcnt wait (T4): literal immediate via if constexpr dispatch
template <int N>
__device__ __forceinline__ void vmwait() {
  if constexpr (N == 0) asm volatile("s_waitcnt vmcnt(0)" ::: "memory");
  else if constexpr (N == 4) asm volatile("s_waitcnt vmcnt(4)" ::: "memory");
  else asm volatile("s_waitcnt vmcnt(6)" ::: "memory");
}
// raw barrier with compiler fences (rule #18 guards)
__device__ __forceinline__ void phase_barrier() {
  __builtin_amdgcn_sched_barrier(0);
  __builtin_amdgcn_s_barrier();
  __builtin_amdgcn_sched_barrier(0);
  asm volatile("" ::: "memory");
}

#define TSTR 71  // transpose stride (64x64 tiles)

// ---------------- prep: split A into bf16 h/m/l (+transposed); init V col0 / U row0 ----------------
__global__ __launch_bounds__(256) void prep(const float* __restrict__ A,
    const float* __restrict__ Bv, const float* __restrict__ Cv,
    ushort_t* __restrict__ Ah, ushort_t* __restrict__ Am, ushort_t* __restrict__ Al,
    ushort_t* __restrict__ ATh, ushort_t* __restrict__ ATm, ushort_t* __restrict__ ATl,
    float* __restrict__ Vc, float* __restrict__ U) {
  __shared__ ushort_t Lt[3 * 64 * TSTR];
  const int tid = threadIdx.x;
  if (blockIdx.x >= 256) {  // init blocks
    int i = (blockIdx.x - 256) * 256 + tid;
    if (i < HDIM) Vc[i] = Bv[i];
    else U[i - HDIM] = Cv[i - HDIM];
    return;
  }
  const int row0 = (blockIdx.x >> 4) * 64, col0 = (blockIdx.x & 15) * 64;
  const int r = tid >> 2, q = tid & 3;
  ushort_t hs[16], ms[16], ls[16];
#pragma unroll
  for (int c4 = 0; c4 < 4; ++c4) {
    float4 a = *(const float4*)&A[(row0 + r) * HDIM + col0 + q * 16 + c4 * 4];
    float av[4] = {a.x, a.y, a.z, a.w};
#pragma unroll
    for (int i = 0; i < 4; ++i) {
      float z = av[i];
      ushort_t h = f2bf(z); float r1 = z - bf2f(h);
      ushort_t mq = f2bf(r1); float r2 = r1 - bf2f(mq);
      ushort_t lq = f2bf(r2);
      hs[c4 * 4 + i] = h; ms[c4 * 4 + i] = mq; ls[c4 * 4 + i] = lq;
    }
  }
  size_t go = (size_t)(row0 + r) * HDIM + col0 + q * 16;
  *(uint4*)&Ah[go] = ((uint4*)hs)[0]; *(uint4*)&Ah[go + 8] = ((uint4*)hs)[1];
  *(uint4*)&Am[go] = ((uint4*)ms)[0]; *(uint4*)&Am[go + 8] = ((uint4*)ms)[1];
  *(uint4*)&Al[go] = ((uint4*)ls)[0]; *(uint4*)&Al[go + 8] = ((uint4*)ls)[1];
#pragma unroll
  for (int i = 0; i < 16; ++i) {
    int c = q * 16 + i;
    Lt[0 * 64 * TSTR + r * TSTR + c] = hs[i];
    Lt[1 * 64 * TSTR + r * TSTR + c] = ms[i];
    Lt[2 * 64 * TSTR + r * TSTR + c] = ls[i];
  }
  __syncthreads();
  const int c = tid >> 2, q2 = tid & 3;
  ushort_t* dsts[3] = {ATh, ATm, ATl};
#pragma unroll
  for (int s = 0; s < 3; ++s) {
    ushort_t tmp[16];
#pragma unroll
    for (int rr = 0; rr < 16; ++rr) tmp[rr] = Lt[s * 64 * TSTR + (q2 * 16 + rr) * TSTR + c];
    size_t gt = (size_t)(col0 + c) * HDIM + row0 + q2 * 16;
    *(uint4*)&dsts[s][gt] = ((uint4*)tmp)[0];
    *(uint4*)&dsts[s][gt + 8] = ((uint4*)tmp)[1];
  }
}

// ---------------- Z = X*X, 64x64 tiles (256 blocks, XCD-swizzled) + fused V/U tail ----------------
// K-loop: 3-buffer, 2-step-ahead pipeline. Counted s_waitcnt vmcnt(NARR) + raw s_barrier
// per K-step (T3/T4): next buffer's loads retire at the wait while the buffer-after-next's
// stay in flight — staging latency hides under a full K-step of compute. R8 profile showed
// the old 2-buf __syncthreads (implicit vmcnt(0) drain) left sq latency-stalled at
// MfmaUtil 9.6% with 1 wave/SIMD after tail blocks retire.
// Hazards: with 3 bufs + 1 barrier/step, writes at step s hit buf (s-1)%3 whose readers all
// passed the step s-1 barrier after register-consuming their ds_reads. Numerics: identical
// k-order and MFMA sequence as R5 (FOUR = SIX minus l-split) -> bit-identical output.
template <int MODE, int NC, bool SIX, bool WRITEL, bool WROW>
__global__ __launch_bounds__(256) void sq_mfma(
    const ushort_t* __restrict__ Xh, const ushort_t* __restrict__ Xm,
    const ushort_t* __restrict__ Xl,
    const ushort_t* __restrict__ XTh, const ushort_t* __restrict__ XTm,
    const ushort_t* __restrict__ XTl,
    ushort_t* __restrict__ Zh, ushort_t* __restrict__ Zm, ushort_t* __restrict__ Zl,
    ushort_t* __restrict__ ZTh, ushort_t* __restrict__ ZTm, ushort_t* __restrict__ ZTl,
    const float* __restrict__ Af, const float* __restrict__ Bvf,
    float* __restrict__ VU) {
  constexpr int NARR = SIX ? 6 : 4;
  constexpr int SLAB = 64 * 32;                 // 2048 elems = 4 KB per array per K-step
  constexpr int BUFSTR = NARR * SLAB;
  constexpr int BBASE = (SIX ? 3 : 2) * SLAB;   // B-side slabs start here
  constexpr int LDS_ELEMS = 3 * BUFSTR;         // SIX: 72 KB (2 blk/CU), FOUR: 48 KB (3 blk/CU)
  __shared__ __align__(16) ushort_t sm[LDS_ELEMS];  // epilogue transpose (13632 elems) reuses
  const int tid = threadIdx.x;

  if (blockIdx.x >= 256) {  // ---- tail blocks: 256 blocks -> 1024 waves ----
    const int tb = blockIdx.x - 256;
    const int wv = tb * 4 + (tid >> 6);
    const int lane = tid & 63;
    if (MODE == 0) {
      float acc = 0.f;
      for (int k = lane; k < HDIM; k += 64) acc += Af[(size_t)wv * HDIM + k] * Bvf[k];
      for (int off = 32; off; off >>= 1) acc += __shfl_down(acc, off);
      if (lane == 0) VU[HDIM + wv] = acc;
    } else {
      const ushort_t* Ph = (MODE == 1) ? Xh : XTh;
      const ushort_t* Pm = (MODE == 1) ? Xm : XTm;
      float acc[NC];
#pragma unroll
      for (int n = 0; n < NC; ++n) acc[n] = 0.f;
      for (int k = lane; k < HDIM; k += 64) {
        float a = bf2f(Ph[(size_t)wv * HDIM + k]) + bf2f(Pm[(size_t)wv * HDIM + k]);
#pragma unroll
        for (int n = 0; n < NC; ++n) acc[n] += a * VU[(size_t)n * HDIM + k];
      }
#pragma unroll
      for (int n = 0; n < NC; ++n) {
        float s = acc[n];
        for (int off = 32; off; off >>= 1) s += __shfl_down(s, off);
        if (lane == 0) VU[(size_t)(NC + n) * HDIM + wv] = s;
      }
    }
    return;
  }

  // ---- squaring blocks: 16x16 grid of 64x64 tiles, XCD-rectangle swizzle ----
  const int bb = blockIdx.x;
  const int xcd = bb & 7, slot = bb >> 3;
  const int tr = 4 * (xcd >> 1) + (slot >> 3);
  const int tc = 8 * (xcd & 1) + (slot & 7);
  const int row0 = tr * 64, col0 = tc * 64;

  const int w = tid >> 6, l = tid & 63, li = l & 15, quad = l >> 4;
  const int sr = tid >> 2, sq4 = tid & 3;

  floatx4 acc0 = {0.f, 0.f, 0.f, 0.f}, acc1 = acc0, acc2 = acc0, acc3 = acc0;

  const int aoff = (w * 16 + li) * 32 + quad * 8;
  const int b0o = (0 * 16 + li) * 32 + quad * 8;
  const int b1o = (1 * 16 + li) * 32 + quad * 8;
  const int b2o = (2 * 16 + li) * 32 + quad * 8;
  const int b3o = (3 * 16 + li) * 32 + quad * 8;

  const ushort_t* gAh = Xh + (size_t)(row0 + sr) * HDIM + sq4 * 8;
  const ushort_t* gAm = Xm + (size_t)(row0 + sr) * HDIM + sq4 * 8;
  const ushort_t* gAl = Xl + (size_t)(row0 + sr) * HDIM + sq4 * 8;
  const ushort_t* gBh = XTh + (size_t)(col0 + sr) * HDIM + sq4 * 8;
  const ushort_t* gBm = XTm + (size_t)(col0 + sr) * HDIM + sq4 * 8;
  const ushort_t* gBl = XTl + (size_t)(col0 + sr) * HDIM + sq4 * 8;

  ushort_t* lwb = &sm[w * 512];  // per-wave uniform LDS base (linear dest)

#define STAGE(BUF, K)                                                          \
  {                                                                            \
    ushort_t* lb = lwb + (BUF) * BUFSTR;                                       \
    const int kk = (K);                                                        \
    gload16(gAh + kk, lb);                                                     \
    gload16(gAm + kk, lb + SLAB);                                              \
    if (SIX) gload16(gAl + kk, lb + 2 * SLAB);                                 \
    gload16(gBh + kk, lb + BBASE);                                             \
    gload16(gBm + kk, lb + BBASE + SLAB);                                      \
    if (SIX) gload16(gBl + kk, lb + BBASE + 2 * SLAB);                         \
  }

  // prologue: fill buffers 0 and 1; wait until buf0's NARR loads retire (buf1's stay in flight)
  STAGE(0, 0)
  STAGE(1, 32)
  vmwait<NARR>();
  phase_barrier();

  int cur = 0, nx2 = 2;
  for (int k0 = 0; k0 < HDIM; k0 += 32) {
    if (k0 + 64 < HDIM) STAGE(nx2, k0 + 64)
    const int cb = cur * BUFSTR;
    bf16x8 ah = *(const bf16x8*)&sm[cb + aoff];
    bf16x8 am = *(const bf16x8*)&sm[cb + SLAB + aoff];
    bf16x8 al;
    if (SIX) al = *(const bf16x8*)&sm[cb + 2 * SLAB + aoff];
    {
      bf16x8 bh = *(const bf16x8*)&sm[cb + BBASE + b0o];
      bf16x8 bm = *(const bf16x8*)&sm[cb + BBASE + SLAB + b0o];
      acc0 = __builtin_amdgcn_mfma_f32_16x16x32_bf16(ah, bh, acc0, 0, 0, 0);
      acc0 = __builtin_amdgcn_mfma_f32_16x16x32_bf16(ah, bm, acc0, 0, 0, 0);
      acc0 = __builtin_amdgcn_mfma_f32_16x16x32_bf16(am, bh, acc0, 0, 0, 0);
      acc0 = __builtin_amdgcn_mfma_f32_16x16x32_bf16(am, bm, acc0, 0, 0, 0);
      if (SIX) {
        bf16x8 bl = *(const bf16x8*)&sm[cb + BBASE + 2 * SLAB + b0o];
        acc0 = __builtin_amdgcn_mfma_f32_16x16x32_bf16(ah, bl, acc0, 0, 0, 0);
        acc0 = __builtin_amdgcn_mfma_f32_16x16x32_bf16(al, bh, acc0, 0, 0, 0);
      }
    }
    {
      bf16x8 bh = *(const bf16x8*)&sm[cb + BBASE + b1o];
      bf16x8 bm = *(const bf16x8*)&sm[cb + BBASE + SLAB + b1o];
      acc1 = __builtin_amdgcn_mfma_f32_16x16x32_bf16(ah, bh, acc1, 0, 0, 0);
      acc1 = __builtin_amdgcn_mfma_f32_16x16x32_bf16(ah, bm, acc1, 0, 0, 0);
      acc1 = __builtin_amdgcn_mfma_f32_16x16x32_bf16(am, bh, acc1, 0, 0, 0);
      acc1 = __builtin_amdgcn_mfma_f32_16x16x32_bf16(am, bm, acc1, 0, 0, 0);
      if (SIX) {
        bf16x8 bl = *(const bf16x8*)&sm[cb + BBASE + 2 * SLAB + b1o];
        acc1 = __builtin_amdgcn_mfma_f32_16x16x32_bf16(ah, bl, acc1, 0, 0, 0);
        acc1 = __builtin_amdgcn_mfma_f32_16x16x32_bf16(al, bh, acc1, 0, 0, 0);
      }
    }
    {
      bf16x8 bh = *(const bf16x8*)&sm[cb + BBASE + b2o];
      bf16x8 bm = *(const bf16x8*)&sm[cb + BBASE + SLAB + b2o];
      acc2 = __builtin_amdgcn_mfma_f32_16x16x32_bf16(ah, bh, acc2, 0, 0, 0);
      acc2 = __builtin_amdgcn_mfma_f32_16x16x32_bf16(ah, bm, acc2, 0, 0, 0);
      acc2 = __builtin_amdgcn_mfma_f32_16x16x32_bf16(am, bh, acc2, 0, 0, 0);
      acc2 = __builtin_amdgcn_mfma_f32_16x16x32_bf16(am, bm, acc2, 0, 0, 0);
      if (SIX) {
        bf16x8 bl = *(const bf16x8*)&sm[cb + BBASE + 2 * SLAB + b2o];
        acc2 = __builtin_amdgcn_mfma_f32_16x16x32_bf16(ah, bl, acc2, 0, 0, 0);
        acc2 = __builtin_amdgcn_mfma_f32_16x16x32_bf16(al, bh, acc2, 0, 0, 0);
      }
    }
    {
      bf16x8 bh = *(const bf16x8*)&sm[cb + BBASE + b3o];
      bf16x8 bm = *(const bf16x8*)&sm[cb + BBASE + SLAB + b3o];
      acc3 = __builtin_amdgcn_mfma_f32_16x16x32_bf16(ah, bh, acc3, 0, 0, 0);
      acc3 = __builtin_amdgcn_mfma_f32_16x16x32_bf16(ah, bm, acc3, 0, 0, 0);
      acc3 = __builtin_amdgcn_mfma_f32_16x16x32_bf16(am, bh, acc3, 0, 0, 0);
      acc3 = __builtin_amdgcn_mfma_f32_16x16x32_bf16(am, bm, acc3, 0, 0, 0);
      if (SIX) {
        bf16x8 bl = *(const bf16x8*)&sm[cb + BBASE + 2 * SLAB + b3o];
        acc3 = __builtin_amdgcn_mfma_f32_16x16x32_bf16(ah, bl, acc3, 0, 0, 0);
        acc3 = __builtin_amdgcn_mfma_f32_16x16x32_bf16(al, bh, acc3, 0, 0, 0);
      }
    }
    // counted wait: retire next buffer's NARR loads; buffer-after-next's stay in flight
    asm volatile("" ::: "memory");
    if (k0 + 64 < HDIM) vmwait<NARR>(); else vmwait<0>();
    phase_barrier();
    cur = (cur == 2) ? 0 : cur + 1;
    nx2 = (nx2 == 2) ? 0 : nx2 + 1;
  }
#undef STAGE

  // ---- epilogue: split, store row-major + LDS-transposed splits ----
  floatx4 accs[4] = {acc0, acc1, acc2, acc3};
#pragma unroll
  for (int j = 0; j < 4; ++j) {
#pragma unroll
    for (int e = 0; e < 4; ++e) {
      float z = accs[j][e];
      int rl = w * 16 + quad * 4 + e;
      int cl = j * 16 + li;
      size_t go = (size_t)(row0 + rl) * HDIM + col0 + cl;
      ushort_t h = f2bf(z); float r1 = z - bf2f(h);
      ushort_t mq = f2bf(r1);
      if (WROW) { Zh[go] = h; Zm[go] = mq; }
      sm[0 * 64 * TSTR + rl * TSTR + cl] = h;
      sm[1 * 64 * TSTR + rl * TSTR + cl] = mq;
      if (WRITEL) {
        ushort_t lq = f2bf(r1 - bf2f(mq));
        if (WROW) Zl[go] = lq;
        sm[2 * 64 * TSTR + rl * TSTR + cl] = lq;
      }
    }
  }
  __syncthreads();
  const int c = tid >> 2, q2 = tid & 3;
  ushort_t* dsts[3] = {ZTh, ZTm, ZTl};
  const int npass = WRITEL ? 3 : 2;
#pragma unroll
  for (int s = 0; s < 3; ++s) {
    if (s >= npass) break;
    ushort_t tmp[16];
#pragma unroll
    for (int rr = 0; rr < 16; ++rr) tmp[rr] = sm[s * 64 * TSTR + (q2 * 16 + rr) * TSTR + c];
    size_t gt = (size_t)(col0 + c) * HDIM + row0 + q2 * 16;
    *(uint4*)&dsts[s][gt] = ((uint4*)tmp)[0];
    *(uint4*)&dsts[s][gt + 8] = ((uint4*)tmp)[1];
  }
}

// ---------------- U extension: rows dst..dst+7 = rows dst-8..dst-1 x A^512 ----------------
__global__ __launch_bounds__(256) void utail8(const ushort_t* __restrict__ PTh,
                                              const ushort_t* __restrict__ PTm,
                                              float* __restrict__ U, int dstbase) {
  const int wv = blockIdx.x * 4 + (threadIdx.x >> 6);
  const int lane = threadIdx.x & 63;
  float acc[8];
#pragma unroll
  for (int m = 0; m < 8; ++m) acc[m] = 0.f;
  const float* Usrc = U + (size_t)(dstbase - 8) * HDIM;
  for (int k = lane; k < HDIM; k += 64) {
    float a = bf2f(PTh[(size_t)wv * HDIM + k]) + bf2f(PTm[(size_t)wv * HDIM + k]);
#pragma unroll
    for (int m = 0; m < 8; ++m) acc[m] += a * Usrc[(size_t)m * HDIM + k];
  }
#pragma unroll
  for (int m = 0; m < 8; ++m) {
    float s = acc[m];
    for (int off = 32; off; off >>= 1) s += __shfl_down(s, off);
    if (lane == 0) U[(size_t)(dstbase + m) * HDIM + wv] = s;
  }
}

// ---------------- K[m] = U row (m>>6) . V col (m&63) ----------------
__global__ __launch_bounds__(256) void wavedotK(const float* __restrict__ U,
                                                const float* __restrict__ Vc,
                                                float* __restrict__ Km) {
  int wv = (blockIdx.x * blockDim.x + threadIdx.x) >> 6;
  int lane = threadIdx.x & 63;
  if (wv >= 32 * 64) return;
  int mr = wv >> 6;
  int nc = wv & 63;
  float s = 0.f;
  for (int k = lane; k < HDIM; k += 64) s += U[mr * HDIM + k] * Vc[nc * HDIM + k];
  for (int off = 32; off; off >>= 1) s += __shfl_down(s, off);
  if (lane == 0) Km[wv] = s;
}

// ---------------- causal conv, LDS-tiled, 4-way split accumulator ----------------
__global__ __launch_bounds__(256) void convk2(const float* __restrict__ u,
                                              const float* __restrict__ Km,
                                              const float* __restrict__ Dv,
                                              float* __restrict__ y) {
  __shared__ float ks[256];
  __shared__ float us[512];
  const int tt = threadIdx.x;
  const int t0 = blockIdx.x * 256;
  const int b = blockIdx.y;
  const float* ub = u + (size_t)b * TLEN;
  const int t = t0 + tt;
  float s0 = Dv[0] * ub[t], s1 = 0.f, s2 = 0.f, s3 = 0.f;
  for (int mc = 0; mc <= t0; mc += 256) {
    __syncthreads();
    ks[tt] = Km[mc + tt];
    int w0 = t0 - mc - 255;
    int g0 = w0 + tt;
    us[tt] = (g0 >= 0) ? ub[g0] : 0.f;
    int g1 = w0 + 256 + tt;
    us[256 + tt] = (g1 < TLEN) ? ub[g1] : 0.f;
    __syncthreads();
    if (mc < t0) {
#pragma unroll 4
      for (int r = 0; r < 256; r += 4) {
        float4 kv = *(const float4*)&ks[r];
        s0 += kv.x * us[tt - r + 255];
        s1 += kv.y * us[tt - r + 254];
        s2 += kv.z * us[tt - r + 253];
        s3 += kv.w * us[tt - r + 252];
      }
    } else {
      for (int r = 0; r <= tt; ++r) s0 += ks[r] * us[tt - r + 255];
    }
  }
  y[(size_t)b * TLEN + t] = s0 + s1 + s2 + s3;
}

extern "C" void kernel_launch(void* const* d_in, const int* in_sizes, int n_in,
                              void* d_out, int out_size, void* d_ws, size_t ws_size,
                              hipStream_t stream) {
  const float* u  = (const float*)d_in[0];
  const float* A  = (const float*)d_in[1];
  const float* Bv = (const float*)d_in[2];
  const float* Cv = (const float*)d_in[3];
  const float* Dv = (const float*)d_in[4];
  float* out = (float*)d_out;

  char* wsb = (char*)d_ws;
  size_t off = 0;
  ushort_t* S[2][6];
  for (int s = 0; s < 2; ++s)
    for (int a = 0; a < 6; ++a) { S[s][a] = (ushort_t*)(wsb + off); off += (size_t)2 << 20; }
  float* Vc = (float*)(wsb + off); off += 64 * HDIM * 4;
  float* U  = (float*)(wsb + off); off += 32 * HDIM * 4;
  float* Km = (float*)(wsb + off); off += TLEN * 4;

  const dim3 gsq(512);  // 256 squaring blocks (swizzled) + 256 tail blocks

#define SQ(MODE, NC, SIX, WRL, WROW, IN, OUT, VU)                              \
  sq_mfma<MODE, NC, SIX, WRL, WROW><<<gsq, 256, 0, stream>>>(                  \
      S[IN][0], S[IN][1], S[IN][2], S[IN][3], S[IN][4], S[IN][5],              \
      S[OUT][0], S[OUT][1], S[OUT][2], S[OUT][3], S[OUT][4], S[OUT][5],        \
      A, Bv, VU)

  prep<<<dim3(264), 256, 0, stream>>>(A, Bv, Cv,
      S[0][0], S[0][1], S[0][2], S[0][3], S[0][4], S[0][5], Vc, U);

  SQ(0, 1,  true,  true,  true,  0, 1, Vc);  // A^2    ; tail: V col1 = A*Bv
  SQ(1, 2,  true,  true,  true,  1, 0, Vc);  // A^4    ; tail: V cols 2,3    (A^2)
  SQ(1, 4,  true,  true,  true,  0, 1, Vc);  // A^8    ; tail: V cols 4..7   (A^4)
  SQ(1, 8,  true,  false, true,  1, 0, Vc);  // A^16   ; tail: V cols 8..15  (A^8)
  SQ(1, 16, false, false, true,  0, 1, Vc);  // A^32   ; tail: V cols 16..31 (A^16)
  SQ(1, 32, false, false, true,  1, 0, Vc);  // A^64   ; tail: V cols 32..63 (A^32)
  SQ(2, 1,  false, false, true,  0, 1, U);   // A^128  ; tail: U row 1       (A^64)
  SQ(2, 2,  false, false, true,  1, 0, U);   // A^256  ; tail: U rows 2,3    (A^128)
  SQ(2, 4,  false, false, false, 0, 1, U);   // A^512  ; tail: U rows 4..7   (A^256); row-major unused
#undef SQ

  // U rows 8..31 via A^512 (S[1] transposed splits), sequential x3
  utail8<<<dim3(256), 256, 0, stream>>>(S[1][3], S[1][4], U, 8);
  utail8<<<dim3(256), 256, 0, stream>>>(S[1][3], S[1][4], U, 16);
  utail8<<<dim3(256), 256, 0, stream>>>(S[1][3], S[1][4], U, 24);

  wavedotK<<<dim3(512), 256, 0, stream>>>(U, Vc, Km);
  convk2<<<dim3(TLEN / 256, NBATCH), 256, 0, stream>>>(u, Km, Dv, out);
}

// Round 10
// 299.652 us; speedup vs baseline: 1.3603x; 1.0076x over previous
//
#include <hip/hip_runtime.h>

#define HDIM 1024
#define TLEN 2048
#define NBATCH 16

typedef short bf16x8 __attribute__((ext_vector_type(8)));
typedef float floatx4 __attribute__((ext_vector_type(4)));
typedef unsigned short ushort_t;

__device__ __forceinline__ ushort_t f2bf(float x) {
  unsigned u = __float_as_uint(x);
  unsigned r = (u + 0x7FFFu + ((u >> 16) & 1u)) >> 16;
  return (ushort_t)r;
}
__device__ __forceinline__ float bf2f(ushort_t h) {
  return __uint_as_float(((unsigned)h) << 16);
}

// async global->LDS, 16B per lane; LDS dest = wave-uniform base + lane*16 (linear)
typedef __attribute__((address_space(1))) void gvoid_t;
typedef __attribute__((address_space(3))) void lvoid_t;
__device__ __forceinline__ void gload16(const ushort_t* g, ushort_t* l) {
  __builtin_amdgcn_global_load_lds((gvoid_t*)g, (lvoid_t*)l, 16, 0, 0);
}

// counted vmcnt wait (T4): literal immediate via if constexpr dispatch
template <int N>
__device__ __forceinline__ void vmwait() {
  if constexpr (N == 0) asm volatile("s_waitcnt vmcnt(0)" ::: "memory");
  else if constexpr (N == 4) asm volatile("s_waitcnt vmcnt(4)" ::: "memory");
  else asm volatile("s_waitcnt vmcnt(6)" ::: "memory");
}
// raw barrier with compiler fences (rule #18 guards)
__device__ __forceinline__ void phase_barrier() {
  __builtin_amdgcn_sched_barrier(0);
  __builtin_amdgcn_s_barrier();
  __builtin_amdgcn_sched_barrier(0);
  asm volatile("" ::: "memory");
}

#define TSTR 71  // transpose stride (64x64 tiles)

// ---------------- prep: split A into bf16 h/m/l (+transposed); init V col0 / U row0 ----------------
__global__ __launch_bounds__(256) void prep(const float* __restrict__ A,
    const float* __restrict__ Bv, const float* __restrict__ Cv,
    ushort_t* __restrict__ Ah, ushort_t* __restrict__ Am, ushort_t* __restrict__ Al,
    ushort_t* __restrict__ ATh, ushort_t* __restrict__ ATm, ushort_t* __restrict__ ATl,
    float* __restrict__ Vc, float* __restrict__ U) {
  __shared__ ushort_t Lt[3 * 64 * TSTR];
  const int tid = threadIdx.x;
  if (blockIdx.x >= 256) {  // init blocks
    int i = (blockIdx.x - 256) * 256 + tid;
    if (i < HDIM) Vc[i] = Bv[i];
    else U[i - HDIM] = Cv[i - HDIM];
    return;
  }
  const int row0 = (blockIdx.x >> 4) * 64, col0 = (blockIdx.x & 15) * 64;
  const int r = tid >> 2, q = tid & 3;
  ushort_t hs[16], ms[16], ls[16];
#pragma unroll
  for (int c4 = 0; c4 < 4; ++c4) {
    float4 a = *(const float4*)&A[(row0 + r) * HDIM + col0 + q * 16 + c4 * 4];
    float av[4] = {a.x, a.y, a.z, a.w};
#pragma unroll
    for (int i = 0; i < 4; ++i) {
      float z = av[i];
      ushort_t h = f2bf(z); float r1 = z - bf2f(h);
      ushort_t mq = f2bf(r1); float r2 = r1 - bf2f(mq);
      ushort_t lq = f2bf(r2);
      hs[c4 * 4 + i] = h; ms[c4 * 4 + i] = mq; ls[c4 * 4 + i] = lq;
    }
  }
  size_t go = (size_t)(row0 + r) * HDIM + col0 + q * 16;
  *(uint4*)&Ah[go] = ((uint4*)hs)[0]; *(uint4*)&Ah[go + 8] = ((uint4*)hs)[1];
  *(uint4*)&Am[go] = ((uint4*)ms)[0]; *(uint4*)&Am[go + 8] = ((uint4*)ms)[1];
  *(uint4*)&Al[go] = ((uint4*)ls)[0]; *(uint4*)&Al[go + 8] = ((uint4*)ls)[1];
#pragma unroll
  for (int i = 0; i < 16; ++i) {
    int c = q * 16 + i;
    Lt[0 * 64 * TSTR + r * TSTR + c] = hs[i];
    Lt[1 * 64 * TSTR + r * TSTR + c] = ms[i];
    Lt[2 * 64 * TSTR + r * TSTR + c] = ls[i];
  }
  __syncthreads();
  const int c = tid >> 2, q2 = tid & 3;
  ushort_t* dsts[3] = {ATh, ATm, ATl};
#pragma unroll
  for (int s = 0; s < 3; ++s) {
    ushort_t tmp[16];
#pragma unroll
    for (int rr = 0; rr < 16; ++rr) tmp[rr] = Lt[s * 64 * TSTR + (q2 * 16 + rr) * TSTR + c];
    size_t gt = (size_t)(col0 + c) * HDIM + row0 + q2 * 16;
    *(uint4*)&dsts[s][gt] = ((uint4*)tmp)[0];
    *(uint4*)&dsts[s][gt + 8] = ((uint4*)tmp)[1];
  }
}

// ---------------- Z = X*X, 64x64 tiles (256 blocks, XCD-swizzled) + fused V/U tail ----------------
// 8 WAVES per GEMM block (512 threads): each wave owns a 16x32 sub-tile (2 accs). Per-SIMD MFMA
// work per K-step unchanged, but 2 waves/SIMD interleave -> ds_read/MFMA latency overlapped.
// (R8 profile: 4-wave blocks = 1 wave/SIMD after tails retire -> MfmaUtil 9.6%, Occ 11%,
// everything latency-exposed. R9's counted-vmcnt alone was neutral; occupancy is the lever.)
// K-loop keeps R9's 3-buffer counted-vmcnt pipeline; staging on waves 0-3 (wave-uniform branch).
// Numerics: per-output-element MFMA sequence and k-order identical to R5/R9 -> bit-identical.
template <int MODE, int NC, bool SIX, bool WRITEL, bool WROW>
__global__ __launch_bounds__(512) void sq_mfma(
    const ushort_t* __restrict__ Xh, const ushort_t* __restrict__ Xm,
    const ushort_t* __restrict__ Xl,
    const ushort_t* __restrict__ XTh, const ushort_t* __restrict__ XTm,
    const ushort_t* __restrict__ XTl,
    ushort_t* __restrict__ Zh, ushort_t* __restrict__ Zm, ushort_t* __restrict__ Zl,
    ushort_t* __restrict__ ZTh, ushort_t* __restrict__ ZTm, ushort_t* __restrict__ ZTl,
    const float* __restrict__ Af, const float* __restrict__ Bvf,
    float* __restrict__ VU) {
  constexpr int NARR = SIX ? 6 : 4;
  constexpr int SLAB = 64 * 32;                 // 2048 elems = 4 KB per array per K-step
  constexpr int BUFSTR = NARR * SLAB;
  constexpr int BBASE = (SIX ? 3 : 2) * SLAB;   // B-side slabs start here
  constexpr int LDS_ELEMS = 3 * BUFSTR;         // SIX: 72 KB, FOUR: 48 KB
  __shared__ __align__(16) ushort_t sm[LDS_ELEMS];  // epilogue transpose (13632 elems) reuses
  const int tid = threadIdx.x;

  if (blockIdx.x >= 256) {  // ---- tail blocks: 128 blocks x 8 waves -> 1024 waves ----
    const int tb = blockIdx.x - 256;
    const int wv = tb * 8 + (tid >> 6);
    const int lane = tid & 63;
    if (MODE == 0) {
      float acc = 0.f;
      for (int k = lane; k < HDIM; k += 64) acc += Af[(size_t)wv * HDIM + k] * Bvf[k];
      for (int off = 32; off; off >>= 1) acc += __shfl_down(acc, off);
      if (lane == 0) VU[HDIM + wv] = acc;
    } else {
      const ushort_t* Ph = (MODE == 1) ? Xh : XTh;
      const ushort_t* Pm = (MODE == 1) ? Xm : XTm;
      float acc[NC];
#pragma unroll
      for (int n = 0; n < NC; ++n) acc[n] = 0.f;
      for (int k = lane; k < HDIM; k += 64) {
        float a = bf2f(Ph[(size_t)wv * HDIM + k]) + bf2f(Pm[(size_t)wv * HDIM + k]);
#pragma unroll
        for (int n = 0; n < NC; ++n) acc[n] += a * VU[(size_t)n * HDIM + k];
      }
#pragma unroll
      for (int n = 0; n < NC; ++n) {
        float s = acc[n];
        for (int off = 32; off; off >>= 1) s += __shfl_down(s, off);
        if (lane == 0) VU[(size_t)(NC + n) * HDIM + wv] = s;
      }
    }
    return;
  }

  // ---- squaring blocks: 16x16 grid of 64x64 tiles, XCD-rectangle swizzle ----
  const int bb = blockIdx.x;
  const int xcd = bb & 7, slot = bb >> 3;
  const int tr = 4 * (xcd >> 1) + (slot >> 3);
  const int tc = 8 * (xcd & 1) + (slot & 7);
  const int row0 = tr * 64, col0 = tc * 64;

  const int w = tid >> 6, l = tid & 63, li = l & 15, quad = l >> 4;
  const int wr = w >> 1, wc = w & 1;             // wave's 16-row block, 32-col block
  const int sr = (tid & 255) >> 2, sq4 = tid & 3;  // staging coords (waves 0-3)

  floatx4 acc0 = {0.f, 0.f, 0.f, 0.f}, acc1 = acc0;

  const int aoff = (wr * 16 + li) * 32 + quad * 8;
  const int b0o = (wc * 32 + li) * 32 + quad * 8;
  const int b1o = (wc * 32 + 16 + li) * 32 + quad * 8;

  const ushort_t* gAh = Xh + (size_t)(row0 + sr) * HDIM + sq4 * 8;
  const ushort_t* gAm = Xm + (size_t)(row0 + sr) * HDIM + sq4 * 8;
  const ushort_t* gAl = Xl + (size_t)(row0 + sr) * HDIM + sq4 * 8;
  const ushort_t* gBh = XTh + (size_t)(col0 + sr) * HDIM + sq4 * 8;
  const ushort_t* gBm = XTm + (size_t)(col0 + sr) * HDIM + sq4 * 8;
  const ushort_t* gBl = XTl + (size_t)(col0 + sr) * HDIM + sq4 * 8;

  ushort_t* lwb = &sm[w * 512];  // staging wave's uniform LDS base (waves 0-3 only)

#define STAGE(BUF, K)                                                          \
  {                                                                            \
    ushort_t* lb = lwb + (BUF) * BUFSTR;                                       \
    const int kk = (K);                                                        \
    gload16(gAh + kk, lb);                                                     \
    gload16(gAm + kk, lb + SLAB);                                              \
    if (SIX) gload16(gAl + kk, lb + 2 * SLAB);                                 \
    gload16(gBh + kk, lb + BBASE);                                             \
    gload16(gBm + kk, lb + BBASE + SLAB);                                      \
    if (SIX) gload16(gBl + kk, lb + BBASE + 2 * SLAB);                         \
  }

  // prologue: fill buffers 0 and 1 (staging waves); wait buf0's loads, buf1's stay in flight
  if (tid < 256) {
    STAGE(0, 0)
    STAGE(1, 32)
  }
  vmwait<NARR>();
  phase_barrier();

  int cur = 0, nx2 = 2;
  for (int k0 = 0; k0 < HDIM; k0 += 32) {
    if (tid < 256 && k0 + 64 < HDIM) STAGE(nx2, k0 + 64)
    const int cb = cur * BUFSTR;
    bf16x8 ah = *(const bf16x8*)&sm[cb + aoff];
    bf16x8 am = *(const bf16x8*)&sm[cb + SLAB + aoff];
    bf16x8 al;
    if (SIX) al = *(const bf16x8*)&sm[cb + 2 * SLAB + aoff];
    {
      bf16x8 bh = *(const bf16x8*)&sm[cb + BBASE + b0o];
      bf16x8 bm = *(const bf16x8*)&sm[cb + BBASE + SLAB + b0o];
      acc0 = __builtin_amdgcn_mfma_f32_16x16x32_bf16(ah, bh, acc0, 0, 0, 0);
      acc0 = __builtin_amdgcn_mfma_f32_16x16x32_bf16(ah, bm, acc0, 0, 0, 0);
      acc0 = __builtin_amdgcn_mfma_f32_16x16x32_bf16(am, bh, acc0, 0, 0, 0);
      acc0 = __builtin_amdgcn_mfma_f32_16x16x32_bf16(am, bm, acc0, 0, 0, 0);
      if (SIX) {
        bf16x8 bl = *(const bf16x8*)&sm[cb + BBASE + 2 * SLAB + b0o];
        acc0 = __builtin_amdgcn_mfma_f32_16x16x32_bf16(ah, bl, acc0, 0, 0, 0);
        acc0 = __builtin_amdgcn_mfma_f32_16x16x32_bf16(al, bh, acc0, 0, 0, 0);
      }
    }
    {
      bf16x8 bh = *(const bf16x8*)&sm[cb + BBASE + b1o];
      bf16x8 bm = *(const bf16x8*)&sm[cb + BBASE + SLAB + b1o];
      acc1 = __builtin_amdgcn_mfma_f32_16x16x32_bf16(ah, bh, acc1, 0, 0, 0);
      acc1 = __builtin_amdgcn_mfma_f32_16x16x32_bf16(ah, bm, acc1, 0, 0, 0);
      acc1 = __builtin_amdgcn_mfma_f32_16x16x32_bf16(am, bh, acc1, 0, 0, 0);
      acc1 = __builtin_amdgcn_mfma_f32_16x16x32_bf16(am, bm, acc1, 0, 0, 0);
      if (SIX) {
        bf16x8 bl = *(const bf16x8*)&sm[cb + BBASE + 2 * SLAB + b1o];
        acc1 = __builtin_amdgcn_mfma_f32_16x16x32_bf16(ah, bl, acc1, 0, 0, 0);
        acc1 = __builtin_amdgcn_mfma_f32_16x16x32_bf16(al, bh, acc1, 0, 0, 0);
      }
    }
    // counted wait: retire next buffer's loads; buffer-after-next's stay in flight
    asm volatile("" ::: "memory");
    if (k0 + 64 < HDIM) vmwait<NARR>(); else vmwait<0>();
    phase_barrier();
    cur = (cur == 2) ? 0 : cur + 1;
    nx2 = (nx2 == 2) ? 0 : nx2 + 1;
  }
#undef STAGE

  // ---- epilogue: split, store row-major + LDS-transposed splits ----
  floatx4 accs[2] = {acc0, acc1};
#pragma unroll
  for (int j = 0; j < 2; ++j) {
#pragma unroll
    for (int e = 0; e < 4; ++e) {
      float z = accs[j][e];
      int rl = wr * 16 + quad * 4 + e;
      int cl = wc * 32 + j * 16 + li;
      size_t go = (size_t)(row0 + rl) * HDIM + col0 + cl;
      ushort_t h = f2bf(z); float r1 = z - bf2f(h);
      ushort_t mq = f2bf(r1);
      if (WROW) { Zh[go] = h; Zm[go] = mq; }
      sm[0 * 64 * TSTR + rl * TSTR + cl] = h;
      sm[1 * 64 * TSTR + rl * TSTR + cl] = mq;
      if (WRITEL) {
        ushort_t lq = f2bf(r1 - bf2f(mq));
        if (WROW) Zl[go] = lq;
        sm[2 * 64 * TSTR + rl * TSTR + cl] = lq;
      }
    }
  }
  __syncthreads();
  const int c = tid >> 3, q3 = tid & 7;  // 512 threads: 64 cols x 8 row-chunks of 8
  ushort_t* dsts[3] = {ZTh, ZTm, ZTl};
  const int npass = WRITEL ? 3 : 2;
#pragma unroll
  for (int s = 0; s < 3; ++s) {
    if (s >= npass) break;
    ushort_t tmp[8];
#pragma unroll
    for (int rr = 0; rr < 8; ++rr) tmp[rr] = sm[s * 64 * TSTR + (q3 * 8 + rr) * TSTR + c];
    size_t gt = (size_t)(col0 + c) * HDIM + row0 + q3 * 8;
    *(uint4*)&dsts[s][gt] = *(uint4*)tmp;
  }
}

// ---------------- U extension: rows dst..dst+7 = rows dst-8..dst-1 x A^512 ----------------
__global__ __launch_bounds__(256) void utail8(const ushort_t* __restrict__ PTh,
                                              const ushort_t* __restrict__ PTm,
                                              float* __restrict__ U, int dstbase) {
  const int wv = blockIdx.x * 4 + (threadIdx.x >> 6);
  const int lane = threadIdx.x & 63;
  float acc[8];
#pragma unroll
  for (int m = 0; m < 8; ++m) acc[m] = 0.f;
  const float* Usrc = U + (size_t)(dstbase - 8) * HDIM;
  for (int k = lane; k < HDIM; k += 64) {
    float a = bf2f(PTh[(size_t)wv * HDIM + k]) + bf2f(PTm[(size_t)wv * HDIM + k]);
#pragma unroll
    for (int m = 0; m < 8; ++m) acc[m] += a * Usrc[(size_t)m * HDIM + k];
  }
#pragma unroll
  for (int m = 0; m < 8; ++m) {
    float s = acc[m];
    for (int off = 32; off; off >>= 1) s += __shfl_down(s, off);
    if (lane == 0) U[(size_t)(dstbase + m) * HDIM + wv] = s;
  }
}

// ---------------- K[m] = U row (m>>6) . V col (m&63) ----------------
__global__ __launch_bounds__(256) void wavedotK(const float* __restrict__ U,
                                                const float* __restrict__ Vc,
                                                float* __restrict__ Km) {
  int wv = (blockIdx.x * blockDim.x + threadIdx.x) >> 6;
  int lane = threadIdx.x & 63;
  if (wv >= 32 * 64) return;
  int mr = wv >> 6;
  int nc = wv & 63;
  float s = 0.f;
  for (int k = lane; k < HDIM; k += 64) s += U[mr * HDIM + k] * Vc[nc * HDIM + k];
  for (int off = 32; off; off >>= 1) s += __shfl_down(s, off);
  if (lane == 0) Km[wv] = s;
}

// ---------------- causal conv, LDS-tiled, 4-way split accumulator ----------------
__global__ __launch_bounds__(256) void convk2(const float* __restrict__ u,
                                              const float* __restrict__ Km,
                                              const float* __restrict__ Dv,
                                              float* __restrict__ y) {
  __shared__ float ks[256];
  __shared__ float us[512];
  const int tt = threadIdx.x;
  const int t0 = blockIdx.x * 256;
  const int b = blockIdx.y;
  const float* ub = u + (size_t)b * TLEN;
  const int t = t0 + tt;
  float s0 = Dv[0] * ub[t], s1 = 0.f, s2 = 0.f, s3 = 0.f;
  for (int mc = 0; mc <= t0; mc += 256) {
    __syncthreads();
    ks[tt] = Km[mc + tt];
    int w0 = t0 - mc - 255;
    int g0 = w0 + tt;
    us[tt] = (g0 >= 0) ? ub[g0] : 0.f;
    int g1 = w0 + 256 + tt;
    us[256 + tt] = (g1 < TLEN) ? ub[g1] : 0.f;
    __syncthreads();
    if (mc < t0) {
#pragma unroll 4
      for (int r = 0; r < 256; r += 4) {
        float4 kv = *(const float4*)&ks[r];
        s0 += kv.x * us[tt - r + 255];
        s1 += kv.y * us[tt - r + 254];
        s2 += kv.z * us[tt - r + 253];
        s3 += kv.w * us[tt - r + 252];
      }
    } else {
      for (int r = 0; r <= tt; ++r) s0 += ks[r] * us[tt - r + 255];
    }
  }
  y[(size_t)b * TLEN + t] = s0 + s1 + s2 + s3;
}

extern "C" void kernel_launch(void* const* d_in, const int* in_sizes, int n_in,
                              void* d_out, int out_size, void* d_ws, size_t ws_size,
                              hipStream_t stream) {
  const float* u  = (const float*)d_in[0];
  const float* A  = (const float*)d_in[1];
  const float* Bv = (const float*)d_in[2];
  const float* Cv = (const float*)d_in[3];
  const float* Dv = (const float*)d_in[4];
  float* out = (float*)d_out;

  char* wsb = (char*)d_ws;
  size_t off = 0;
  ushort_t* S[2][6];
  for (int s = 0; s < 2; ++s)
    for (int a = 0; a < 6; ++a) { S[s][a] = (ushort_t*)(wsb + off); off += (size_t)2 << 20; }
  float* Vc = (float*)(wsb + off); off += 64 * HDIM * 4;
  float* U  = (float*)(wsb + off); off += 32 * HDIM * 4;
  float* Km = (float*)(wsb + off); off += TLEN * 4;

  const dim3 gsq(384);  // 256 squaring blocks (swizzled, 512 thr) + 128 tail blocks (8 waves)

#define SQ(MODE, NC, SIX, WRL, WROW, IN, OUT, VU)                              \
  sq_mfma<MODE, NC, SIX, WRL, WROW><<<gsq, 512, 0, stream>>>(                  \
      S[IN][0], S[IN][1], S[IN][2], S[IN][3], S[IN][4], S[IN][5],              \
      S[OUT][0], S[OUT][1], S[OUT][2], S[OUT][3], S[OUT][4], S[OUT][5],        \
      A, Bv, VU)

  prep<<<dim3(264), 256, 0, stream>>>(A, Bv, Cv,
      S[0][0], S[0][1], S[0][2], S[0][3], S[0][4], S[0][5], Vc, U);

  SQ(0, 1,  true,  true,  true,  0, 1, Vc);  // A^2    ; tail: V col1 = A*Bv
  SQ(1, 2,  true,  true,  true,  1, 0, Vc);  // A^4    ; tail: V cols 2,3    (A^2)
  SQ(1, 4,  true,  true,  true,  0, 1, Vc);  // A^8    ; tail: V cols 4..7   (A^4)
  SQ(1, 8,  true,  false, true,  1, 0, Vc);  // A^16   ; tail: V cols 8..15  (A^8)
  SQ(1, 16, false, false, true,  0, 1, Vc);  // A^32   ; tail: V cols 16..31 (A^16)
  SQ(1, 32, false, false, true,  1, 0, Vc);  // A^64   ; tail: V cols 32..63 (A^32)
  SQ(2, 1,  false, false, true,  0, 1, U);   // A^128  ; tail: U row 1       (A^64)
  SQ(2, 2,  false, false, true,  1, 0, U);   // A^256  ; tail: U rows 2,3    (A^128)
  SQ(2, 4,  false, false, false, 0, 1, U);   // A^512  ; tail: U rows 4..7   (A^256); row-major unused
#undef SQ

  // U rows 8..31 via A^512 (S[1] transposed splits), sequential x3
  utail8<<<dim3(256), 256, 0, stream>>>(S[1][3], S[1][4], U, 8);
  utail8<<<dim3(256), 256, 0, stream>>>(S[1][3], S[1][4], U, 16);
  utail8<<<dim3(256), 256, 0, stream>>>(S[1][3], S[1][4], U, 24);

  wavedotK<<<dim3(512), 256, 0, stream>>>(U, Vc, Km);
  convk2<<<dim3(TLEN / 256, NBATCH), 256, 0, stream>>>(u, Km, Dv, out);
}